// Round 2
// baseline (2009.659 us; speedup 1.0000x reference)
//
#include <hip/hip_runtime.h>
#include <math.h>

#define HF 128
#define NB 9216          // nodes per batch (96*96)
#define BB 2
#define MROWS (BB*NB)    // 18432
#define GH 96
#define GW 96
#define LAYERS 6

__device__ __forceinline__ float swishf(float x) {
    // x * sigmoid(x) = x / (1 + e^-x)
    return __fdividef(x, 1.0f + __expf(-x));
}

// ---------------- build nodein [B,N,14] = [u(12) | pos(2)] ----------------
__global__ void k_build(const float* __restrict__ x, const float* __restrict__ pos,
                        float* __restrict__ nodein) {
    int idx = blockIdx.x * 256 + threadIdx.x;
    if (idx >= MROWS) return;
    int b = idx / NB, n = idx - b * NB;
    float* o = nodein + (size_t)idx * 14;
    const float* xb = x + (size_t)b * 12 * NB + n;
#pragma unroll
    for (int k = 0; k < 12; ++k) o[k] = xb[(size_t)k * NB];
    o[12] = pos[2 * n];
    o[13] = pos[2 * n + 1];
}

// ---------------- small-K GEMM: out[M,128] = act(X[M,K] @ W[K,128] (+bias)) ----------------
template<int K, int ACT>
__global__ void k_smallk(const float* __restrict__ X, int ldx,
                         const float* __restrict__ W,
                         const float* __restrict__ bias,
                         float* __restrict__ out) {
    __shared__ float xs[32][K];
    int row0 = blockIdx.x * 32;
    int t = threadIdx.x;
    for (int idx = t; idx < 32 * K; idx += 256) {
        int r = idx / K, k = idx - r * K;
        xs[r][k] = X[(size_t)(row0 + r) * ldx + k];
    }
    __syncthreads();
    int f = t & 127, rh = t >> 7;
    float wreg[K];
#pragma unroll
    for (int k = 0; k < K; ++k) wreg[k] = W[k * HF + f];
    float bv = bias ? bias[f] : 0.0f;
    for (int r = rh; r < 32; r += 2) {
        float acc = bv;
#pragma unroll
        for (int k = 0; k < K; ++k) acc = fmaf(xs[r][k], wreg[k], acc);
        if (ACT) acc = swishf(acc);
        out[(size_t)(row0 + r) * HF + f] = acc;
    }
}

// ---------------- generic 128-K GEMM, 64 rows x 64 feats per block ----------------
// out[row][f] = [post +] act( X1@W1 [+ X2@W2] [+ bias] [+ preScale*pre] )
// optional deterministic per-block stats partials (sum, sumsq per feature)
__device__ __forceinline__ void gemm_core(
    const float* __restrict__ X1, const float* __restrict__ W1,
    const float* __restrict__ X2, const float* __restrict__ W2,
    const float* __restrict__ bias,
    const float* __restrict__ pre, float preScale,
    const float* __restrict__ post,
    float* __restrict__ out,
    float* __restrict__ partial,
    int act, int row0, int f0)
{
    __shared__ float xs[HF][68];   // X^T tile [k][r], 64 rows + pad (16B-aligned rows)
    __shared__ float ws[HF][64];   // W slice  [k][j]
    __shared__ float ssum[16][64];
    __shared__ float ssq[16][64];
    int t = threadIdx.x;
    int fg = t & 15, rg = t >> 4;            // 16 fgroups x 16 rowgroups
    float acc[4][4] = {};
    int npass = X2 ? 2 : 1;
    for (int s = 0; s < npass; ++s) {
        const float* Xp = s ? X2 : X1;
        const float* Wp = s ? W2 : W1;
        if (s) __syncthreads();
        const float* Xb = Xp + (size_t)row0 * HF;
#pragma unroll
        for (int i = 0; i < 32; ++i) {
            int idx = i * 256 + t;
            int k = idx & 127, r = idx >> 7;
            xs[k][r] = Xb[(size_t)r * HF + k];
        }
        // ws is 128x64 = 8192 elements -> 32 iterations of 256 threads
#pragma unroll
        for (int i = 0; i < 32; ++i) {
            int idx = i * 256 + t;
            int k = idx >> 6, j = idx & 63;
            ws[k][j] = Wp[(size_t)k * HF + f0 + j];
        }
        __syncthreads();
#pragma unroll 4
        for (int k = 0; k < HF; ++k) {
            const float4 xv = *(const float4*)&xs[k][rg * 4];
            const float4 wv = *(const float4*)&ws[k][fg * 4];
            float xa[4] = {xv.x, xv.y, xv.z, xv.w};
            float wa[4] = {wv.x, wv.y, wv.z, wv.w};
#pragma unroll
            for (int i = 0; i < 4; ++i)
#pragma unroll
                for (int j = 0; j < 4; ++j)
                    acc[i][j] = fmaf(xa[i], wa[j], acc[i][j]);
        }
    }
    float bv[4];
#pragma unroll
    for (int j = 0; j < 4; ++j) bv[j] = bias ? bias[f0 + fg * 4 + j] : 0.0f;
    float lsum[4] = {0, 0, 0, 0}, lsq[4] = {0, 0, 0, 0};
#pragma unroll
    for (int i = 0; i < 4; ++i) {
        int row = row0 + rg * 4 + i;
        size_t base = (size_t)row * HF + f0 + fg * 4;
        float v[4];
#pragma unroll
        for (int j = 0; j < 4; ++j) v[j] = acc[i][j] + bv[j];
        if (pre) {
            float4 p = *(const float4*)&pre[base];
            v[0] += preScale * p.x; v[1] += preScale * p.y;
            v[2] += preScale * p.z; v[3] += preScale * p.w;
        }
        if (act) {
#pragma unroll
            for (int j = 0; j < 4; ++j) v[j] = swishf(v[j]);
        }
        if (post) {
            float4 p = *(const float4*)&post[base];
            v[0] += p.x; v[1] += p.y; v[2] += p.z; v[3] += p.w;
        }
        *(float4*)&out[base] = make_float4(v[0], v[1], v[2], v[3]);
        if (partial) {
#pragma unroll
            for (int j = 0; j < 4; ++j) { lsum[j] += v[j]; lsq[j] += v[j] * v[j]; }
        }
    }
    if (partial) {
        // deterministic block reduction over 16 rowgroups
#pragma unroll
        for (int j = 0; j < 4; ++j) {
            ssum[rg][fg * 4 + j] = lsum[j];
            ssq[rg][fg * 4 + j]  = lsq[j];
        }
        __syncthreads();
        if (t < 64) {
            float s = 0.f, q = 0.f;
#pragma unroll
            for (int i = 0; i < 16; ++i) { s += ssum[i][t]; q += ssq[i][t]; }
            int tile = row0 >> 6;
            float* p = partial + ((size_t)tile * HF + f0 + t) * 2;
            p[0] = s; p[1] = q;
        }
    }
}

__global__ __launch_bounds__(256, 2)
void k_gemm(const float* __restrict__ X1, const float* __restrict__ W1,
            const float* __restrict__ X2, const float* __restrict__ W2,
            const float* __restrict__ bias, const float* __restrict__ pre, float preScale,
            const float* __restrict__ post, float* __restrict__ out,
            float* __restrict__ partial, int act) {
    gemm_core(X1, W1, X2, W2, bias, pre, preScale, post, out, partial, act,
              blockIdx.x * 64, blockIdx.y * 64);
}

// A = hf@W1a + Au ; S = hf@W1b - Au   (grid.y: 0,1 -> A halves; 2,3 -> S halves)
__global__ __launch_bounds__(256, 2)
void k_gemm_as(const float* __restrict__ hf, const float* __restrict__ msgw1,
               const float* __restrict__ Au, float* __restrict__ A, float* __restrict__ S) {
    int fs = blockIdx.y;
    int f0 = (fs & 1) * 64;
    const float* W = msgw1 + (size_t)(fs >> 1) * (HF * HF);
    float* out = (fs >> 1) ? S : A;
    float sc = (fs >> 1) ? -1.0f : 1.0f;
    gemm_core(hf, W, nullptr, nullptr, nullptr, Au, sc, nullptr, out, nullptr, 0,
              blockIdx.x * 64, f0);
}

// ---------------- message + aggregate: 9-point stencil gather ----------------
// agg[b,dst,:] = (1/deg) * sum_{valid off} swish( swish(A[dst]+S[src]+D[off]) @ W2 + b2 )
__global__ __launch_bounds__(256, 1)
void k_agg(const float* __restrict__ A, const float* __restrict__ S,
           const float* __restrict__ W2, const float* __restrict__ b2,
           const float* __restrict__ b1, const float* __restrict__ w1d,
           float* __restrict__ agg) {
    __shared__ float ws[HF][HF];     // 64KB: msg second-layer weights
    __shared__ float zs[HF][36];     // z1^T tile [k][r], 32 rows + pad (16B-aligned)
    __shared__ float as[32][HF];     // A tile
    __shared__ float ds[3][HF];      // D per dist type
    int t = threadIdx.x;
    int bidx = blockIdx.x;
    int b = bidx / (NB / 32);
    int tile = bidx - b * (NB / 32);
    int n0 = tile * 32;              // 96 = 3*32 -> tile stays within one grid row
    int R = n0 / GW;
    int C0 = n0 - R * GW;
#pragma unroll
    for (int i = 0; i < 64; ++i) {
        int idx = i * 256 + t;
        ws[idx >> 7][idx & 127] = W2[idx];
    }
    const float* Ab = A + ((size_t)b * NB + n0) * HF;
#pragma unroll
    for (int i = 0; i < 16; ++i) {
        int idx = i * 256 + t;
        int k = idx & 127, r = idx >> 7;
        as[r][k] = Ab[(size_t)r * HF + k];
    }
    if (t < 128) {
        float bb = b1[t], wd = w1d[t];
        ds[0][t] = bb;
        ds[1][t] = fmaf(1.0f / 95.0f, wd, bb);
        ds[2][t] = fmaf(1.4142135623730951f / 95.0f, wd, bb);
    }
    __syncthreads();
    int fg = t & 31, rg = t >> 5;    // 32 fgroups(128 feats) x 8 rowgroups(32 rows)
    const float4 b2v = *(const float4*)&b2[fg * 4];
    float acc[4][4] = {};
    const float* Sb = S + (size_t)b * NB * HF;
    for (int off = 0; off < 9; ++off) {
        int dr = off / 3 - 1, dc = off % 3 - 1;
        if (R + dr < 0 || R + dr >= GH) continue;   // block-uniform
        int dn = dr * GW + dc;
        int dd = dr * dr + dc * dc;                 // 0,1,2 -> dist type
        __syncthreads();                            // zs free from previous GEMM
#pragma unroll
        for (int i = 0; i < 16; ++i) {
            int idx = i * 256 + t;
            int k = idx & 127, r = idx >> 7;
            int src = n0 + r + dn;
            src = min(max(src, 0), NB - 1);         // clamp; invalid lanes masked later
            float z = as[r][k] + Sb[(size_t)src * HF + k] + ds[dd][k];
            zs[k][r] = swishf(z);
        }
        __syncthreads();
        float s2[4][4] = {};
#pragma unroll 4
        for (int k = 0; k < HF; ++k) {
            const float4 zv = *(const float4*)&zs[k][rg * 4];
            const float4 wv = *(const float4*)&ws[k][fg * 4];
            float za[4] = {zv.x, zv.y, zv.z, zv.w};
            float wa[4] = {wv.x, wv.y, wv.z, wv.w};
#pragma unroll
            for (int i = 0; i < 4; ++i)
#pragma unroll
                for (int j = 0; j < 4; ++j)
                    s2[i][j] = fmaf(za[i], wa[j], s2[i][j]);
        }
#pragma unroll
        for (int i = 0; i < 4; ++i) {
            int c = C0 + rg * 4 + i;
            if ((unsigned)(c + dc) < (unsigned)GW) {
                acc[i][0] += swishf(s2[i][0] + b2v.x);
                acc[i][1] += swishf(s2[i][1] + b2v.y);
                acc[i][2] += swishf(s2[i][2] + b2v.z);
                acc[i][3] += swishf(s2[i][3] + b2v.w);
            }
        }
    }
    float nr = 1.0f + (R > 0) + (R < GH - 1);
#pragma unroll
    for (int i = 0; i < 4; ++i) {
        int r = rg * 4 + i;
        int c = C0 + r;
        float nc = 1.0f + (c > 0) + (c < GW - 1);
        float inv = 1.0f / (nr * nc);
        float4 o = make_float4(acc[i][0] * inv, acc[i][1] * inv,
                               acc[i][2] * inv, acc[i][3] * inv);
        *(float4*)&agg[((size_t)b * NB + n0 + r) * HF + fg * 4] = o;
    }
}

// ---------------- instance-norm stats reduce (1 block) ----------------
__global__ void k_stats(const float* __restrict__ partial, float* __restrict__ musig) {
    int t = threadIdx.x;             // 256 = b*128 + f
    int b = t >> 7, f = t & 127;
    float s = 0.f, q = 0.f;
    for (int i = 0; i < 144; ++i) {
        const float* p = partial + ((size_t)(b * 144 + i) * HF + f) * 2;
        s += p[0]; q += p[1];
    }
    float mu = s * (1.0f / NB);
    float var = q * (1.0f / NB) - mu * mu;
    musig[t] = mu;
    musig[256 + t] = rsqrtf(var + 1e-5f);
}

__global__ void k_norm(float* __restrict__ hf, const float* __restrict__ musig) {
    int idx = blockIdx.x * 256 + threadIdx.x;     // per float4
    if (idx >= MROWS * HF / 4) return;
    int b = (idx >= NB * HF / 4) ? 1 : 0;
    int f = (idx * 4) & 127;
    float4 v = ((const float4*)hf)[idx];
    const float* mu = musig + b * 128 + f;
    const float* rs = musig + 256 + b * 128 + f;
    v.x = (v.x - mu[0]) * rs[0];
    v.y = (v.y - mu[1]) * rs[1];
    v.z = (v.z - mu[2]) * rs[2];
    v.w = (v.w - mu[3]) * rs[3];
    ((float4*)hf)[idx] = v;
}

// ---------------- output head: diff = g1 @ out_w2 + b2 ; out = x[:,-1] + diff ----------------
__global__ void k_out2(const float* __restrict__ g1, const float* __restrict__ w2,
                       const float* __restrict__ b2, const float* __restrict__ x,
                       float* __restrict__ out) {
    __shared__ float gs[64][HF];
    int row0 = blockIdx.x * 64;
    int t = threadIdx.x;
#pragma unroll
    for (int i = 0; i < 32; ++i) {
        int idx = i * 256 + t;
        int r = idx >> 7, k = idx & 127;
        gs[r][k] = g1[(size_t)(row0 + r) * HF + k];
    }
    __syncthreads();
    if (t < 192) {
        int r = t / 3, c = t - (t / 3) * 3;
        int row = row0 + r;
        int b = row / NB, n = row - b * NB;
        float acc = b2[c];
#pragma unroll 8
        for (int k = 0; k < HF; ++k) acc = fmaf(gs[r][k], w2[k * 3 + c], acc);
        float xv = x[(((size_t)b * 4 + 3) * 3 + c) * NB + n];
        out[((size_t)b * 3 + c) * NB + n] = acc + xv;
    }
}

extern "C" void kernel_launch(void* const* d_in, const int* in_sizes, int n_in,
                              void* d_out, int out_size, void* d_ws, size_t ws_size,
                              hipStream_t stream) {
    const float* x      = (const float*)d_in[0];
    const float* pos    = (const float*)d_in[3];
    const float* emb_w1 = (const float*)d_in[4];
    const float* emb_b1 = (const float*)d_in[5];
    const float* emb_w2 = (const float*)d_in[6];
    const float* emb_b2 = (const float*)d_in[7];
    const float* msg_w1 = (const float*)d_in[8];
    const float* msg_b1 = (const float*)d_in[9];
    const float* msg_w2 = (const float*)d_in[10];
    const float* msg_b2 = (const float*)d_in[11];
    const float* upd_w1 = (const float*)d_in[12];
    const float* upd_b1 = (const float*)d_in[13];
    const float* upd_w2 = (const float*)d_in[14];
    const float* upd_b2 = (const float*)d_in[15];
    const float* out_w1 = (const float*)d_in[16];
    const float* out_b1 = (const float*)d_in[17];
    const float* out_w2 = (const float*)d_in[18];
    const float* out_b2 = (const float*)d_in[19];

    float* w = (float*)d_ws;
    size_t off = 0;
    auto alloc = [&](size_t n) { float* p = w + off; off += n; return p; };
    float* nodein  = alloc((size_t)MROWS * 14);
    float* hf      = alloc((size_t)MROWS * HF);
    float* B1      = alloc((size_t)MROWS * HF);   // Au -> agg -> g1
    float* B2      = alloc((size_t)MROWS * HF);   // A
    float* B3      = alloc((size_t)MROWS * HF);   // S
    float* B4      = alloc((size_t)MROWS * HF);   // h1 / t1
    float* partial = alloc((size_t)288 * HF * 2);
    float* musig   = alloc(512);
    (void)ws_size; (void)in_sizes; (void)n_in; (void)out_size;

    k_build<<<(MROWS + 255) / 256, 256, 0, stream>>>(x, pos, nodein);
    k_smallk<14, 1><<<MROWS / 32, 256, 0, stream>>>(nodein, 14, emb_w1, emb_b1, B4);
    k_gemm<<<dim3(288, 2), 256, 0, stream>>>(B4, emb_w2, nullptr, nullptr, emb_b2,
                                             nullptr, 0.f, nullptr, hf, nullptr, 1);
    for (int l = 0; l < LAYERS; ++l) {
        const float* W1 = msg_w1 + (size_t)l * 269 * HF;
        k_smallk<12, 0><<<MROWS / 32, 256, 0, stream>>>(nodein, 14, W1 + 256 * HF,
                                                        nullptr, B1);
        k_gemm_as<<<dim3(288, 4), 256, 0, stream>>>(hf, W1, B1, B2, B3);
        k_agg<<<BB * (NB / 32), 256, 0, stream>>>(B2, B3, msg_w2 + (size_t)l * HF * HF,
                                                  msg_b2 + l * HF, msg_b1 + l * HF,
                                                  W1 + 268 * HF, B1);
        k_gemm<<<dim3(288, 2), 256, 0, stream>>>(hf, upd_w1 + (size_t)l * 256 * HF,
                                                 B1, upd_w1 + (size_t)l * 256 * HF + HF * HF,
                                                 upd_b1 + l * HF, nullptr, 0.f, nullptr,
                                                 B4, nullptr, 1);
        k_gemm<<<dim3(288, 2), 256, 0, stream>>>(B4, upd_w2 + (size_t)l * HF * HF,
                                                 nullptr, nullptr, upd_b2 + l * HF,
                                                 nullptr, 0.f, hf, hf, partial, 1);
        k_stats<<<1, 256, 0, stream>>>(partial, musig);
        k_norm<<<(MROWS * HF / 4 + 255) / 256, 256, 0, stream>>>(hf, musig);
    }
    k_gemm<<<dim3(288, 2), 256, 0, stream>>>(hf, out_w1, nullptr, nullptr, out_b1,
                                             nullptr, 0.f, nullptr, B1, nullptr, 1);
    k_out2<<<MROWS / 64, 256, 0, stream>>>(B1, out_w2, out_b2, x, (float*)d_out);
}

// Round 3
// 880.094 us; speedup vs baseline: 2.2835x; 2.2835x over previous
//
#include <hip/hip_runtime.h>
#include <math.h>

#define HF 128
#define NB 9216          // nodes per batch (96*96)
#define BB 2
#define MROWS (BB*NB)    // 18432
#define GH 96
#define GW 96
#define LAYERS 6

typedef __attribute__((ext_vector_type(8))) short bf16x8;
typedef __attribute__((ext_vector_type(4))) float f32x4;
typedef unsigned short ushort_t;

#define MFMA16(a, b, c) __builtin_amdgcn_mfma_f32_16x16x32_bf16(a, b, c, 0, 0, 0)

__device__ __forceinline__ float swishf(float x) {
    return __fdividef(x, 1.0f + __expf(-x));
}

// fp32 -> bf16 bits, round-to-nearest-even
__device__ __forceinline__ unsigned short f2b(float f) {
    unsigned u = __float_as_uint(f);
    unsigned r = (u + 0x7fffu + ((u >> 16) & 1u)) >> 16;
    return (unsigned short)r;
}

// ---------------- weight prep: wT[slot][col][k] = bf16(W[k][col]) ----------------
// slots: 0=emb_w2, 1=out_w1, 2+6l+{0..5} = msgW1a, msgW1b, msgW2, updW1a, updW1b, updW2
__global__ void k_prep(const float* __restrict__ embw2, const float* __restrict__ outw1,
                       const float* __restrict__ msgw1, const float* __restrict__ msgw2,
                       const float* __restrict__ updw1, const float* __restrict__ updw2,
                       unsigned short* __restrict__ wT) {
    int s = blockIdx.x;
    const float* src;
    if (s == 0) src = embw2;
    else if (s == 1) src = outw1;
    else {
        int l = (s - 2) / 6, r = (s - 2) % 6;
        if (r == 0)      src = msgw1 + (size_t)l * 269 * HF;
        else if (r == 1) src = msgw1 + (size_t)l * 269 * HF + HF * HF;
        else if (r == 2) src = msgw2 + (size_t)l * HF * HF;
        else if (r == 3) src = updw1 + (size_t)l * 256 * HF;
        else if (r == 4) src = updw1 + (size_t)l * 256 * HF + HF * HF;
        else             src = updw2 + (size_t)l * HF * HF;
    }
    __shared__ float tile[128][133];
    int t = threadIdx.x;
#pragma unroll
    for (int i = 0; i < 64; ++i) {
        int id = i * 256 + t;
        tile[id >> 7][id & 127] = src[id];
    }
    __syncthreads();
    unsigned short* o = wT + (size_t)s * 16384;
#pragma unroll
    for (int i = 0; i < 64; ++i) {
        int id = i * 256 + t;
        int col = id >> 7, k = id & 127;
        o[id] = f2b(tile[k][col]);
    }
}

// ---------------- build nodein [B,N,14] = [u(12) | pos(2)] ----------------
__global__ void k_build(const float* __restrict__ x, const float* __restrict__ pos,
                        float* __restrict__ nodein) {
    int idx = blockIdx.x * 256 + threadIdx.x;
    if (idx >= MROWS) return;
    int b = idx / NB, n = idx - b * NB;
    float* o = nodein + (size_t)idx * 14;
    const float* xb = x + (size_t)b * 12 * NB + n;
#pragma unroll
    for (int k = 0; k < 12; ++k) o[k] = xb[(size_t)k * NB];
    o[12] = pos[2 * n];
    o[13] = pos[2 * n + 1];
}

// ---------------- small-K GEMM: out[M,128] = act(X[M,K] @ W[K,128] (+bias)) ----------------
template<int K, int ACT, int BOUT>
__global__ void k_smallk(const float* __restrict__ X, int ldx,
                         const float* __restrict__ W,
                         const float* __restrict__ bias,
                         void* __restrict__ outv) {
    __shared__ float xs[32][K];
    int row0 = blockIdx.x * 32;
    int t = threadIdx.x;
    for (int idx = t; idx < 32 * K; idx += 256) {
        int r = idx / K, k = idx - r * K;
        xs[r][k] = X[(size_t)(row0 + r) * ldx + k];
    }
    __syncthreads();
    int f = t & 127, rh = t >> 7;
    float wreg[K];
#pragma unroll
    for (int k = 0; k < K; ++k) wreg[k] = W[k * HF + f];
    float bv = bias ? bias[f] : 0.0f;
    for (int r = rh; r < 32; r += 2) {
        float acc = bv;
#pragma unroll
        for (int k = 0; k < K; ++k) acc = fmaf(xs[r][k], wreg[k], acc);
        if (ACT) acc = swishf(acc);
        if (BOUT) ((unsigned short*)outv)[(size_t)(row0 + r) * HF + f] = f2b(acc);
        else      ((float*)outv)[(size_t)(row0 + r) * HF + f] = acc;
    }
}

// ---------------- MFMA GEMM: out = [resid +] act( X1@W1 [+ X2@W2] + bias ) ----------------
// X* are bf16 [M][128]; W* are bf16 wT [col][k]. 256 thr, 64 rows/block, no LDS main path.
__global__ __launch_bounds__(256)
void k_mfma(const unsigned short* __restrict__ X1, const unsigned short* __restrict__ W1,
            const unsigned short* __restrict__ X2, const unsigned short* __restrict__ W2,
            const float* __restrict__ bias, const float* __restrict__ resid,
            float* __restrict__ outF, unsigned short* __restrict__ outB,
            float* __restrict__ partial, int act) {
    __shared__ float sp[4][128], sq[4][128];
    int t = threadIdx.x, wave = t >> 6, lane = t & 63, lr = lane & 15, lg = lane >> 4;
    int rw = blockIdx.x * 64 + wave * 16;
    f32x4 acc[8];
#pragma unroll
    for (int j = 0; j < 8; ++j) acc[j] = (f32x4)0.0f;
#pragma unroll
    for (int kc = 0; kc < 4; ++kc) {
        int k0 = kc * 32 + lg * 8;
        bf16x8 a1 = *(const bf16x8*)(X1 + (size_t)(rw + lr) * HF + k0);
        bf16x8 a2;
        if (X2) a2 = *(const bf16x8*)(X2 + (size_t)(rw + lr) * HF + k0);
#pragma unroll
        for (int j = 0; j < 8; ++j) {
            bf16x8 b = *(const bf16x8*)(W1 + (size_t)(j * 16 + lr) * HF + k0);
            acc[j] = MFMA16(a1, b, acc[j]);
            if (X2) {
                bf16x8 b2 = *(const bf16x8*)(W2 + (size_t)(j * 16 + lr) * HF + k0);
                acc[j] = MFMA16(a2, b2, acc[j]);
            }
        }
    }
#pragma unroll
    for (int j = 0; j < 8; ++j) {
        int f = j * 16 + lr;
        float bv = bias ? bias[f] : 0.0f;
        float s1 = 0.f, s2 = 0.f;
#pragma unroll
        for (int r = 0; r < 4; ++r) {
            int row = rw + lg * 4 + r;
            size_t o = (size_t)row * HF + f;
            float v = acc[j][r] + bv;
            if (act) v = swishf(v);
            if (resid) v += resid[o];
            if (outF) outF[o] = v;
            if (outB) outB[o] = f2b(v);
            s1 += v; s2 += v * v;
        }
        if (partial) {
            s1 += __shfl_xor(s1, 16); s1 += __shfl_xor(s1, 32);
            s2 += __shfl_xor(s2, 16); s2 += __shfl_xor(s2, 32);
            if (lg == 0) { sp[wave][f] = s1; sq[wave][f] = s2; }
        }
    }
    if (partial) {
        __syncthreads();
        if (t < 128) {
            float s = sp[0][t] + sp[1][t] + sp[2][t] + sp[3][t];
            float q = sq[0][t] + sq[1][t] + sq[2][t] + sq[3][t];
            float* p = partial + ((size_t)blockIdx.x * HF + t) * 2;
            p[0] = s; p[1] = q;
        }
    }
}

// ---------------- A/S projection: A = hf@W1a + Au ; S = hf@W1b - Au ----------------
__global__ __launch_bounds__(256)
void k_as(const unsigned short* __restrict__ hfb, const unsigned short* __restrict__ wA,
          const unsigned short* __restrict__ wB, const float* __restrict__ Au,
          float* __restrict__ A, float* __restrict__ S) {
    int t = threadIdx.x, wave = t >> 6, lane = t & 63, lr = lane & 15, lg = lane >> 4;
    int rw = blockIdx.x * 64 + wave * 16;
    f32x4 accA[8], accS[8];
#pragma unroll
    for (int j = 0; j < 8; ++j) { accA[j] = (f32x4)0.0f; accS[j] = (f32x4)0.0f; }
#pragma unroll
    for (int kc = 0; kc < 4; ++kc) {
        int k0 = kc * 32 + lg * 8;
        bf16x8 a = *(const bf16x8*)(hfb + (size_t)(rw + lr) * HF + k0);
#pragma unroll
        for (int j = 0; j < 8; ++j) {
            bf16x8 bA = *(const bf16x8*)(wA + (size_t)(j * 16 + lr) * HF + k0);
            accA[j] = MFMA16(a, bA, accA[j]);
            bf16x8 bS = *(const bf16x8*)(wB + (size_t)(j * 16 + lr) * HF + k0);
            accS[j] = MFMA16(a, bS, accS[j]);
        }
    }
#pragma unroll
    for (int j = 0; j < 8; ++j) {
        int f = j * 16 + lr;
#pragma unroll
        for (int r = 0; r < 4; ++r) {
            size_t o = (size_t)(rw + lg * 4 + r) * HF + f;
            float au = Au[o];
            A[o] = accA[j][r] + au;
            S[o] = accS[j][r] - au;
        }
    }
}

// ---------------- message + aggregate (MFMA, 9-point stencil) ----------------
// agg[b,n,:] = (1/deg) * sum_off swish( swish(A[n]+S[n+dn]+D[off]) @ W2 + b2 )
__global__ __launch_bounds__(256)
void k_agg(const float* __restrict__ A, const float* __restrict__ Sg,
           const unsigned short* __restrict__ wT2, const float* __restrict__ b2,
           const float* __restrict__ b1, const float* __restrict__ w1d,
           unsigned short* __restrict__ aggb) {
    __shared__ unsigned short wts[128 * 128];   // W2^T bf16, XOR-swizzled
    __shared__ unsigned short zsb[64 * 128];    // z1 bf16, XOR-swizzled
    __shared__ float dsb[3][128];
    int t = threadIdx.x;
    int b = blockIdx.x / 144, tile = blockIdx.x % 144;
    int n0 = tile * 64;
    size_t bN = (size_t)b * NB;
    char* wb = (char*)wts;
    char* zb = (char*)zsb;
#pragma unroll
    for (int i = 0; i < 8; ++i) {               // stage W2^T (32KB)
        int id = i * 256 + t;
        int col = id >> 4, k8 = (id & 15) * 8;
        uint4 v = *(const uint4*)(wT2 + (size_t)col * HF + k8);
        *(uint4*)(wb + ((col * 256 + k8 * 2) ^ ((col & 7) << 4))) = v;
    }
    if (t < 128) {
        float bb = b1[t], wd = w1d[t];
        dsb[0][t] = bb;
        dsb[1][t] = fmaf(1.0f / 95.0f, wd, bb);
        dsb[2][t] = fmaf(1.4142135623730951f / 95.0f, wd, bb);
    }
    int lane = t & 63, wave = t >> 6, lr = lane & 15, lg = lane >> 4;
    float b2r[8];
#pragma unroll
    for (int j = 0; j < 8; ++j) b2r[j] = b2[j * 16 + lr];
    f32x4 agg[8];
#pragma unroll
    for (int j = 0; j < 8; ++j) agg[j] = (f32x4)0.0f;

    for (int off = 0; off < 9; ++off) {
        int dr = off / 3 - 1, dc = off % 3 - 1;
        int dn = dr * GW + dc, dd = dr * dr + dc * dc;
        __syncthreads();                        // zsb free (and iter0: wts/dsb ready)
#pragma unroll
        for (int i = 0; i < 8; ++i) {           // z1 = swish(A+S+D) -> bf16 LDS
            int id = i * 256 + t;
            int row = id >> 5, k0 = (id & 31) * 4;
            int n = n0 + row;
            int src = n + dn;
            src = min(max(src, 0), NB - 1);
            f32x4 av = *(const f32x4*)(A  + (bN + n)   * HF + k0);
            f32x4 sv = *(const f32x4*)(Sg + (bN + src) * HF + k0);
            unsigned short z[4];
#pragma unroll
            for (int xq = 0; xq < 4; ++xq)
                z[xq] = f2b(swishf(av[xq] + sv[xq] + dsb[dd][k0 + xq]));
            uint2 p;
            p.x = (unsigned)z[0] | ((unsigned)z[1] << 16);
            p.y = (unsigned)z[2] | ((unsigned)z[3] << 16);
            *(uint2*)(zb + ((row * 256 + k0 * 2) ^ ((row & 7) << 4))) = p;
        }
        __syncthreads();
        f32x4 accm[8];
#pragma unroll
        for (int j = 0; j < 8; ++j) accm[j] = (f32x4)0.0f;
#pragma unroll
        for (int kc = 0; kc < 4; ++kc) {
            int k0 = kc * 32 + lg * 8;
            int row = wave * 16 + lr;
            bf16x8 a = *(const bf16x8*)(zb + ((row * 256 + k0 * 2) ^ ((row & 7) << 4)));
#pragma unroll
            for (int j = 0; j < 8; ++j) {
                int col = j * 16 + lr;
                bf16x8 bfr = *(const bf16x8*)(wb + ((col * 256 + k0 * 2) ^ ((col & 7) << 4)));
                accm[j] = MFMA16(a, bfr, accm[j]);
            }
        }
#pragma unroll
        for (int j = 0; j < 8; ++j)
#pragma unroll
            for (int r = 0; r < 4; ++r) {
                int n = n0 + wave * 16 + lg * 4 + r;
                int R = n / GW, C = n - R * GW;
                if ((unsigned)(R + dr) < (unsigned)GH && (unsigned)(C + dc) < (unsigned)GW)
                    agg[j][r] += swishf(accm[j][r] + b2r[j]);
            }
    }
#pragma unroll
    for (int j = 0; j < 8; ++j)
#pragma unroll
        for (int r = 0; r < 4; ++r) {
            int n = n0 + wave * 16 + lg * 4 + r;
            int R = n / GW, C = n - R * GW;
            float nr = 1.0f + (R > 0) + (R < GH - 1);
            float nc = 1.0f + (C > 0) + (C < GW - 1);
            aggb[(bN + n) * HF + j * 16 + lr] = f2b(__fdividef(agg[j][r], nr * nc));
        }
}

// ---------------- instance-norm stats reduce: 256 blocks, one (b,f) each ----------------
__global__ void k_stats(const float* __restrict__ partial, float* __restrict__ musig) {
    __shared__ float ss[256], qq[256];
    int bx = blockIdx.x;
    int b = bx >> 7, f = bx & 127;
    int t = threadIdx.x;
    float s = 0.f, q = 0.f;
    if (t < 144) {
        const float* p = partial + (((size_t)(b * 144 + t)) * HF + f) * 2;
        s = p[0]; q = p[1];
    }
    ss[t] = s; qq[t] = q;
    __syncthreads();
    for (int st = 128; st > 0; st >>= 1) {
        if (t < st) { ss[t] += ss[t + st]; qq[t] += qq[t + st]; }
        __syncthreads();
    }
    if (t == 0) {
        float mu = ss[0] * (1.0f / NB);
        float var = qq[0] * (1.0f / NB) - mu * mu;
        musig[bx] = mu;
        musig[256 + bx] = rsqrtf(var + 1e-5f);
    }
}

__global__ void k_norm(float* __restrict__ hf, const float* __restrict__ musig,
                       unsigned short* __restrict__ hfb) {
    int idx = blockIdx.x * 256 + threadIdx.x;     // per float4
    if (idx >= MROWS * HF / 4) return;
    int b = (idx >= NB * HF / 4) ? 1 : 0;
    int f = (idx * 4) & 127;
    float4 v = ((const float4*)hf)[idx];
    const float* mu = musig + b * 128 + f;
    const float* rs = musig + 256 + b * 128 + f;
    v.x = (v.x - mu[0]) * rs[0];
    v.y = (v.y - mu[1]) * rs[1];
    v.z = (v.z - mu[2]) * rs[2];
    v.w = (v.w - mu[3]) * rs[3];
    ((float4*)hf)[idx] = v;
    uint2 p;
    p.x = (unsigned)f2b(v.x) | ((unsigned)f2b(v.y) << 16);
    p.y = (unsigned)f2b(v.z) | ((unsigned)f2b(v.w) << 16);
    *(uint2*)(hfb + (size_t)idx * 4) = p;
}

// ---------------- output head: diff = g1 @ out_w2 + b2 ; out = x[:,-1] + diff ----------------
__global__ void k_out2(const float* __restrict__ g1, const float* __restrict__ w2,
                       const float* __restrict__ b2, const float* __restrict__ x,
                       float* __restrict__ out) {
    __shared__ float gs[64][HF];
    int row0 = blockIdx.x * 64;
    int t = threadIdx.x;
#pragma unroll
    for (int i = 0; i < 32; ++i) {
        int idx = i * 256 + t;
        int r = idx >> 7, k = idx & 127;
        gs[r][k] = g1[(size_t)(row0 + r) * HF + k];
    }
    __syncthreads();
    if (t < 192) {
        int r = t / 3, c = t - (t / 3) * 3;
        int row = row0 + r;
        int b = row / NB, n = row - b * NB;
        float acc = b2[c];
#pragma unroll 8
        for (int k = 0; k < HF; ++k) acc = fmaf(gs[r][k], w2[k * 3 + c], acc);
        float xv = x[(((size_t)b * 4 + 3) * 3 + c) * NB + n];
        out[((size_t)b * 3 + c) * NB + n] = acc + xv;
    }
}

extern "C" void kernel_launch(void* const* d_in, const int* in_sizes, int n_in,
                              void* d_out, int out_size, void* d_ws, size_t ws_size,
                              hipStream_t stream) {
    const float* x      = (const float*)d_in[0];
    const float* pos    = (const float*)d_in[3];
    const float* emb_w1 = (const float*)d_in[4];
    const float* emb_b1 = (const float*)d_in[5];
    const float* emb_w2 = (const float*)d_in[6];
    const float* emb_b2 = (const float*)d_in[7];
    const float* msg_w1 = (const float*)d_in[8];
    const float* msg_b1 = (const float*)d_in[9];
    const float* msg_w2 = (const float*)d_in[10];
    const float* msg_b2 = (const float*)d_in[11];
    const float* upd_w1 = (const float*)d_in[12];
    const float* upd_b1 = (const float*)d_in[13];
    const float* upd_w2 = (const float*)d_in[14];
    const float* upd_b2 = (const float*)d_in[15];
    const float* out_w1 = (const float*)d_in[16];
    const float* out_b1 = (const float*)d_in[17];
    const float* out_w2 = (const float*)d_in[18];
    const float* out_b2 = (const float*)d_in[19];

    float* w = (float*)d_ws;
    size_t off = 0;
    auto alloc = [&](size_t n) { float* p = w + off; off += n; return p; };
    float* nodein  = alloc((size_t)MROWS * 14);
    float* hf      = alloc((size_t)MROWS * HF);
    float* Au      = alloc((size_t)MROWS * HF);
    float* A       = alloc((size_t)MROWS * HF);   // also g1 at the end
    float* S       = alloc((size_t)MROWS * HF);
    float* partial = alloc((size_t)288 * HF * 2);
    float* musig   = alloc(512);
    unsigned short* hfb  = (unsigned short*)alloc((size_t)MROWS * 64);
    unsigned short* aggb = (unsigned short*)alloc((size_t)MROWS * 64);
    unsigned short* t1b  = (unsigned short*)alloc((size_t)MROWS * 64);  // also h1b
    unsigned short* wT   = (unsigned short*)alloc((size_t)38 * 16384 / 2);
    (void)ws_size; (void)in_sizes; (void)n_in; (void)out_size;

    k_prep<<<38, 256, 0, stream>>>(emb_w2, out_w1, msg_w1, msg_w2, upd_w1, upd_w2, wT);
    k_build<<<(MROWS + 255) / 256, 256, 0, stream>>>(x, pos, nodein);
    // emb layer 1 (K=14, fp32 in, bf16 out)
    k_smallk<14, 1, 1><<<MROWS / 32, 256, 0, stream>>>(nodein, 14, emb_w1, emb_b1, t1b);
    // emb layer 2 (MFMA) -> hf fp32 + hfb bf16
    k_mfma<<<288, 256, 0, stream>>>(t1b, wT + 0 * 16384, nullptr, nullptr,
                                    emb_b2, nullptr, hf, hfb, nullptr, 1);
    for (int l = 0; l < LAYERS; ++l) {
        const unsigned short* wL = wT + (size_t)(2 + 6 * l) * 16384;
        const float* W1 = msg_w1 + (size_t)l * 269 * HF;
        k_smallk<12, 0, 0><<<MROWS / 32, 256, 0, stream>>>(nodein, 14, W1 + 256 * HF,
                                                           nullptr, Au);
        k_as<<<288, 256, 0, stream>>>(hfb, wL + 0 * 16384, wL + 1 * 16384, Au, A, S);
        k_agg<<<288, 256, 0, stream>>>(A, S, wL + 2 * 16384, msg_b2 + l * HF,
                                       msg_b1 + l * HF, W1 + 268 * HF, aggb);
        k_mfma<<<288, 256, 0, stream>>>(hfb, wL + 3 * 16384, aggb, wL + 4 * 16384,
                                        upd_b1 + l * HF, nullptr, nullptr, t1b,
                                        nullptr, 1);
        k_mfma<<<288, 256, 0, stream>>>(t1b, wL + 5 * 16384, nullptr, nullptr,
                                        upd_b2 + l * HF, hf, hf, nullptr,
                                        partial, 1);
        k_stats<<<256, 256, 0, stream>>>(partial, musig);
        k_norm<<<(MROWS * HF / 4 + 255) / 256, 256, 0, stream>>>(hf, musig, hfb);
    }
    // output head layer 1 -> g1 (reuse A)
    k_mfma<<<288, 256, 0, stream>>>(hfb, wT + 1 * 16384, nullptr, nullptr,
                                    out_b1, nullptr, A, nullptr, nullptr, 1);
    k_out2<<<MROWS / 64, 256, 0, stream>>>(A, out_w2, out_b2, x, (float*)d_out);
}

// Round 4
// 811.419 us; speedup vs baseline: 2.4767x; 1.0846x over previous
//
#include <hip/hip_runtime.h>
#include <math.h>

#define HF 128
#define NB 9216          // nodes per batch (96*96)
#define BB 2
#define MROWS (BB*NB)    // 18432
#define GH 96
#define GW 96
#define LAYERS 6

typedef __attribute__((ext_vector_type(8))) short bf16x8;
typedef __attribute__((ext_vector_type(4))) float f32x4;

#define MFMA16(a, b, c) __builtin_amdgcn_mfma_f32_16x16x32_bf16(a, b, c, 0, 0, 0)

__device__ __forceinline__ float swishf(float x) {
    return __fdividef(x, 1.0f + __expf(-x));
}

// fp32 -> bf16 bits, round-to-nearest-even
__device__ __forceinline__ unsigned short f2b(float f) {
    unsigned u = __float_as_uint(f);
    unsigned r = (u + 0x7fffu + ((u >> 16) & 1u)) >> 16;
    return (unsigned short)r;
}
__device__ __forceinline__ float b2f(unsigned short u) {
    return __uint_as_float((unsigned)u << 16);
}

// ---------------- weight prep: wT[slot][col][k] = bf16(W[k][col]) ----------------
// slots: 0=emb_w2, 1=out_w1, 2+6l+{0..5} = msgW1a, msgW1b, msgW2, updW1a, updW1b, updW2
__global__ void k_prep(const float* __restrict__ embw2, const float* __restrict__ outw1,
                       const float* __restrict__ msgw1, const float* __restrict__ msgw2,
                       const float* __restrict__ updw1, const float* __restrict__ updw2,
                       unsigned short* __restrict__ wT) {
    int s = blockIdx.x;
    const float* src;
    if (s == 0) src = embw2;
    else if (s == 1) src = outw1;
    else {
        int l = (s - 2) / 6, r = (s - 2) % 6;
        if (r == 0)      src = msgw1 + (size_t)l * 269 * HF;
        else if (r == 1) src = msgw1 + (size_t)l * 269 * HF + HF * HF;
        else if (r == 2) src = msgw2 + (size_t)l * HF * HF;
        else if (r == 3) src = updw1 + (size_t)l * 256 * HF;
        else if (r == 4) src = updw1 + (size_t)l * 256 * HF + HF * HF;
        else             src = updw2 + (size_t)l * HF * HF;
    }
    __shared__ float tile[128][133];
    int t = threadIdx.x;
#pragma unroll
    for (int i = 0; i < 64; ++i) {
        int id = i * 256 + t;
        tile[id >> 7][id & 127] = src[id];
    }
    __syncthreads();
    unsigned short* o = wT + (size_t)s * 16384;
#pragma unroll
    for (int i = 0; i < 64; ++i) {
        int id = i * 256 + t;
        int col = id >> 7, k = id & 127;
        o[id] = f2b(tile[k][col]);
    }
}

// ---------------- build nodein [B,N,14] = [u(12) | pos(2)] ----------------
__global__ void k_build(const float* __restrict__ x, const float* __restrict__ pos,
                        float* __restrict__ nodein) {
    int idx = blockIdx.x * 256 + threadIdx.x;
    if (idx >= MROWS) return;
    int b = idx / NB, n = idx - b * NB;
    float* o = nodein + (size_t)idx * 14;
    const float* xb = x + (size_t)b * 12 * NB + n;
#pragma unroll
    for (int k = 0; k < 12; ++k) o[k] = xb[(size_t)k * NB];
    o[12] = pos[2 * n];
    o[13] = pos[2 * n + 1];
}

// ---------------- small-K GEMM: out[M,128] = act(X[M,K] @ W[K,128] (+bias)) ----------------
template<int K, int ACT, int BOUT>
__global__ void k_smallk(const float* __restrict__ X, int ldx,
                         const float* __restrict__ W,
                         const float* __restrict__ bias,
                         void* __restrict__ outv) {
    __shared__ float xs[32][K];
    int row0 = blockIdx.x * 32;
    int t = threadIdx.x;
    for (int idx = t; idx < 32 * K; idx += 256) {
        int r = idx / K, k = idx - r * K;
        xs[r][k] = X[(size_t)(row0 + r) * ldx + k];
    }
    __syncthreads();
    int f = t & 127, rh = t >> 7;
    float wreg[K];
#pragma unroll
    for (int k = 0; k < K; ++k) wreg[k] = W[k * HF + f];
    float bv = bias ? bias[f] : 0.0f;
    for (int r = rh; r < 32; r += 2) {
        float acc = bv;
#pragma unroll
        for (int k = 0; k < K; ++k) acc = fmaf(xs[r][k], wreg[k], acc);
        if (ACT) acc = swishf(acc);
        if (BOUT) ((unsigned short*)outv)[(size_t)(row0 + r) * HF + f] = f2b(acc);
        else      ((float*)outv)[(size_t)(row0 + r) * HF + f] = acc;
    }
}

// ---------------- MFMA GEMM (col-split waves): out = [resid +] act( X1@W1 [+ X2@W2] + bias )
// 576 blocks x 256 thr; wave w: rows blockIdx*32 + (w>>1)*16, cols (w&1)*64.
__global__ __launch_bounds__(256)
void k_mfma(const unsigned short* __restrict__ X1, const unsigned short* __restrict__ W1,
            const unsigned short* __restrict__ X2, const unsigned short* __restrict__ W2,
            const float* __restrict__ bias, const float* __restrict__ resid,
            float* __restrict__ outF, unsigned short* __restrict__ outB,
            float* __restrict__ partial, int act) {
    int t = threadIdx.x, wave = t >> 6, lane = t & 63, lr = lane & 15, lg = lane >> 4;
    int rt = blockIdx.x * 32 + (wave >> 1) * 16;
    int fbase = (wave & 1) * 64;
    f32x4 acc[4];
#pragma unroll
    for (int j = 0; j < 4; ++j) acc[j] = (f32x4)0.0f;
#pragma unroll
    for (int kc = 0; kc < 4; ++kc) {
        int k0 = kc * 32 + lg * 8;
        bf16x8 a1 = *(const bf16x8*)(X1 + (size_t)(rt + lr) * HF + k0);
        bf16x8 a2;
        if (X2) a2 = *(const bf16x8*)(X2 + (size_t)(rt + lr) * HF + k0);
#pragma unroll
        for (int j = 0; j < 4; ++j) {
            bf16x8 b = *(const bf16x8*)(W1 + (size_t)(fbase + j * 16 + lr) * HF + k0);
            acc[j] = MFMA16(a1, b, acc[j]);
            if (X2) {
                bf16x8 b2v = *(const bf16x8*)(W2 + (size_t)(fbase + j * 16 + lr) * HF + k0);
                acc[j] = MFMA16(a2, b2v, acc[j]);
            }
        }
    }
#pragma unroll
    for (int j = 0; j < 4; ++j) {
        int f = fbase + j * 16 + lr;
        float bv = bias ? bias[f] : 0.0f;
        float s1 = 0.f, s2 = 0.f;
#pragma unroll
        for (int r = 0; r < 4; ++r) {
            int row = rt + lg * 4 + r;
            size_t o = (size_t)row * HF + f;
            float v = acc[j][r] + bv;
            if (act) v = swishf(v);
            if (resid) v += resid[o];
            if (outF) outF[o] = v;
            if (outB) outB[o] = f2b(v);
            s1 += v; s2 += v * v;
        }
        if (partial) {
            s1 += __shfl_xor(s1, 16); s1 += __shfl_xor(s1, 32);
            s2 += __shfl_xor(s2, 16); s2 += __shfl_xor(s2, 32);
            if (lg == 0) {
                int rowtile = blockIdx.x * 2 + (wave >> 1);
                float* p = partial + ((size_t)rowtile * HF + f) * 2;
                p[0] = s1; p[1] = s2;
            }
        }
    }
}

// ---------------- A/S projection: A = bf16(hf@W1a + Au) ; S = bf16(hf@W1b - Au) ----------------
__global__ __launch_bounds__(256)
void k_as(const unsigned short* __restrict__ hfb, const unsigned short* __restrict__ wA,
          const unsigned short* __restrict__ wB, const float* __restrict__ Au,
          unsigned short* __restrict__ A, unsigned short* __restrict__ S) {
    int t = threadIdx.x, wave = t >> 6, lane = t & 63, lr = lane & 15, lg = lane >> 4;
    int rt = blockIdx.x * 32 + (wave >> 1) * 16;
    int fbase = (wave & 1) * 64;
    f32x4 accA[4], accS[4];
#pragma unroll
    for (int j = 0; j < 4; ++j) { accA[j] = (f32x4)0.0f; accS[j] = (f32x4)0.0f; }
#pragma unroll
    for (int kc = 0; kc < 4; ++kc) {
        int k0 = kc * 32 + lg * 8;
        bf16x8 a = *(const bf16x8*)(hfb + (size_t)(rt + lr) * HF + k0);
#pragma unroll
        for (int j = 0; j < 4; ++j) {
            bf16x8 bA = *(const bf16x8*)(wA + (size_t)(fbase + j * 16 + lr) * HF + k0);
            accA[j] = MFMA16(a, bA, accA[j]);
            bf16x8 bS = *(const bf16x8*)(wB + (size_t)(fbase + j * 16 + lr) * HF + k0);
            accS[j] = MFMA16(a, bS, accS[j]);
        }
    }
#pragma unroll
    for (int j = 0; j < 4; ++j) {
        int f = fbase + j * 16 + lr;
#pragma unroll
        for (int r = 0; r < 4; ++r) {
            size_t o = (size_t)(rt + lg * 4 + r) * HF + f;
            float au = Au[o];
            A[o] = f2b(accA[j][r] + au);
            S[o] = f2b(accS[j][r] - au);
        }
    }
}

// ---------------- message + aggregate (per-wave, barrier-free after init) ----------------
// agg[b,n,:] = (1/deg) * sum_off swish( swish(A[n]+S[n+dn]+D[off]) @ W2 + b2 )
__global__ __launch_bounds__(256, 2)
void k_agg(const unsigned short* __restrict__ Ab, const unsigned short* __restrict__ Sb,
           const unsigned short* __restrict__ wT2, const float* __restrict__ b2,
           const float* __restrict__ b1, const float* __restrict__ w1d,
           unsigned short* __restrict__ aggb) {
    __shared__ float dsb[3][128];
    int t = threadIdx.x, wave = t >> 6, lane = t & 63, lr = lane & 15, lg = lane >> 4;
    int b = blockIdx.x / (NB / 32);
    int tile = blockIdx.x % (NB / 32);
    int rt = tile * 32 + (wave >> 1) * 16;   // 16 rows, same grid row R (32|96, 16|96)
    int fbase = (wave & 1) * 64;
    size_t bN = (size_t)b * NB;
    int R = rt / GW, C0 = rt % GW;

    if (t < 128) {
        float bb = b1[t], wd = w1d[t];
        dsb[0][t] = bb;
        dsb[1][t] = fmaf(1.0f / 95.0f, wd, bb);
        dsb[2][t] = fmaf(1.4142135623730951f / 95.0f, wd, bb);
    }
    // cache W2 fragments for this wave's 64 cols (64 VGPRs)
    bf16x8 w2f[4][4];
#pragma unroll
    for (int j = 0; j < 4; ++j)
#pragma unroll
        for (int kc = 0; kc < 4; ++kc)
            w2f[j][kc] = *(const bf16x8*)(wT2 + (size_t)(fbase + j * 16 + lr) * HF
                                          + kc * 32 + lg * 8);
    // cache A row slice (fp32, 32 VGPRs)
    int rowA = rt + lr;
    float Af[32];
#pragma unroll
    for (int kc = 0; kc < 4; ++kc) {
        bf16x8 av = *(const bf16x8*)(Ab + (bN + rowA) * HF + kc * 32 + lg * 8);
#pragma unroll
        for (int e = 0; e < 8; ++e) Af[kc * 8 + e] = b2f((unsigned short)av[e]);
    }
    float b2r[4];
#pragma unroll
    for (int j = 0; j < 4; ++j) b2r[j] = b2[fbase + j * 16 + lr];
    f32x4 agg[4];
#pragma unroll
    for (int j = 0; j < 4; ++j) agg[j] = (f32x4)0.0f;
    __syncthreads();   // dsb ready; no barriers after this

    // prefetch S for offset 0 (dn=-97)
    bf16x8 sv[4];
    {
        int src = min(max(rowA - 97, 0), NB - 1);
#pragma unroll
        for (int kc = 0; kc < 4; ++kc)
            sv[kc] = *(const bf16x8*)(Sb + (bN + src) * HF + kc * 32 + lg * 8);
    }
#pragma unroll 1
    for (int off = 0; off < 9; ++off) {
        int dr = off / 3 - 1, dc = off % 3 - 1;
        int dd = dr * dr + dc * dc;
        bf16x8 cur[4];
#pragma unroll
        for (int kc = 0; kc < 4; ++kc) cur[kc] = sv[kc];
        if (off < 8) {
            int no = off + 1;
            int dnn = (no / 3 - 1) * GW + (no % 3 - 1);
            int src = min(max(rowA + dnn, 0), NB - 1);
#pragma unroll
            for (int kc = 0; kc < 4; ++kc)
                sv[kc] = *(const bf16x8*)(Sb + (bN + src) * HF + kc * 32 + lg * 8);
        }
        // z1 = swish(A + S + D) -> A-fragments in registers
        bf16x8 afr[4];
#pragma unroll
        for (int kc = 0; kc < 4; ++kc) {
            f32x4 d0 = *(const f32x4*)&dsb[dd][kc * 32 + lg * 8];
            f32x4 d1 = *(const f32x4*)&dsb[dd][kc * 32 + lg * 8 + 4];
            union { bf16x8 v; unsigned u[4]; } az;
#pragma unroll
            for (int q = 0; q < 4; ++q) {
                int e = q * 2;
                float zl = Af[kc * 8 + e]     + b2f((unsigned short)cur[kc][e])     +
                           (e < 4 ? d0[e] : d1[e - 4]);
                float zh = Af[kc * 8 + e + 1] + b2f((unsigned short)cur[kc][e + 1]) +
                           (e + 1 < 4 ? d0[e + 1] : d1[e - 3]);
                az.u[q] = (unsigned)f2b(swishf(zl)) | ((unsigned)f2b(swishf(zh)) << 16);
            }
            afr[kc] = az.v;
        }
        f32x4 acc[4];
#pragma unroll
        for (int j = 0; j < 4; ++j) acc[j] = (f32x4)0.0f;
#pragma unroll
        for (int kc = 0; kc < 4; ++kc)
#pragma unroll
            for (int j = 0; j < 4; ++j)
                acc[j] = MFMA16(afr[kc], w2f[j][kc], acc[j]);
        bool rOK = (unsigned)(R + dr) < (unsigned)GH;
#pragma unroll
        for (int j = 0; j < 4; ++j)
#pragma unroll
            for (int r = 0; r < 4; ++r) {
                int C = C0 + lg * 4 + r;
                if (rOK && (unsigned)(C + dc) < (unsigned)GW)
                    agg[j][r] += swishf(acc[j][r] + b2r[j]);
            }
    }
    float nr = 1.0f + (R > 0) + (R < GH - 1);
#pragma unroll
    for (int j = 0; j < 4; ++j)
#pragma unroll
        for (int r = 0; r < 4; ++r) {
            int n = rt + lg * 4 + r;
            int C = C0 + lg * 4 + r;
            float nc = 1.0f + (C > 0) + (C < GW - 1);
            aggb[(bN + n) * HF + fbase + j * 16 + lr] =
                f2b(__fdividef(agg[j][r], nr * nc));
        }
}

// ---------------- instance-norm stats reduce: 256 blocks, one (b,f) each ----------------
// partial: [1152 rowtiles][128 f][2]; 576 rowtiles per batch
__global__ void k_stats(const float* __restrict__ partial, float* __restrict__ musig) {
    __shared__ float ss[256], qq[256];
    int bx = blockIdx.x;
    int b = bx >> 7, f = bx & 127;
    int t = threadIdx.x;
    float s = 0.f, q = 0.f;
    for (int i = t; i < 576; i += 256) {
        const float* p = partial + (((size_t)(b * 576 + i)) * HF + f) * 2;
        s += p[0]; q += p[1];
    }
    ss[t] = s; qq[t] = q;
    __syncthreads();
    for (int st = 128; st > 0; st >>= 1) {
        if (t < st) { ss[t] += ss[t + st]; qq[t] += qq[t + st]; }
        __syncthreads();
    }
    if (t == 0) {
        float mu = ss[0] * (1.0f / NB);
        float var = qq[0] * (1.0f / NB) - mu * mu;
        musig[bx] = mu;
        musig[256 + bx] = rsqrtf(var + 1e-5f);
    }
}

__global__ void k_norm(float* __restrict__ hf, const float* __restrict__ musig,
                       unsigned short* __restrict__ hfb) {
    int idx = blockIdx.x * 256 + threadIdx.x;     // per float4
    if (idx >= MROWS * HF / 4) return;
    int b = (idx >= NB * HF / 4) ? 1 : 0;
    int f = (idx * 4) & 127;
    float4 v = ((const float4*)hf)[idx];
    const float* mu = musig + b * 128 + f;
    const float* rs = musig + 256 + b * 128 + f;
    v.x = (v.x - mu[0]) * rs[0];
    v.y = (v.y - mu[1]) * rs[1];
    v.z = (v.z - mu[2]) * rs[2];
    v.w = (v.w - mu[3]) * rs[3];
    ((float4*)hf)[idx] = v;
    uint2 p;
    p.x = (unsigned)f2b(v.x) | ((unsigned)f2b(v.y) << 16);
    p.y = (unsigned)f2b(v.z) | ((unsigned)f2b(v.w) << 16);
    *(uint2*)(hfb + (size_t)idx * 4) = p;
}

// ---------------- output head: diff = g1 @ out_w2 + b2 ; out = x[:,-1] + diff ----------------
__global__ void k_out2(const float* __restrict__ g1, const float* __restrict__ w2,
                       const float* __restrict__ b2, const float* __restrict__ x,
                       float* __restrict__ out) {
    __shared__ float gs[64][HF];
    int row0 = blockIdx.x * 64;
    int t = threadIdx.x;
#pragma unroll
    for (int i = 0; i < 32; ++i) {
        int idx = i * 256 + t;
        int r = idx >> 7, k = idx & 127;
        gs[r][k] = g1[(size_t)(row0 + r) * HF + k];
    }
    __syncthreads();
    if (t < 192) {
        int r = t / 3, c = t - (t / 3) * 3;
        int row = row0 + r;
        int b = row / NB, n = row - b * NB;
        float acc = b2[c];
#pragma unroll 8
        for (int k = 0; k < HF; ++k) acc = fmaf(gs[r][k], w2[k * 3 + c], acc);
        float xv = x[(((size_t)b * 4 + 3) * 3 + c) * NB + n];
        out[((size_t)b * 3 + c) * NB + n] = acc + xv;
    }
}

extern "C" void kernel_launch(void* const* d_in, const int* in_sizes, int n_in,
                              void* d_out, int out_size, void* d_ws, size_t ws_size,
                              hipStream_t stream) {
    const float* x      = (const float*)d_in[0];
    const float* pos    = (const float*)d_in[3];
    const float* emb_w1 = (const float*)d_in[4];
    const float* emb_b1 = (const float*)d_in[5];
    const float* emb_w2 = (const float*)d_in[6];
    const float* emb_b2 = (const float*)d_in[7];
    const float* msg_w1 = (const float*)d_in[8];
    const float* msg_b1 = (const float*)d_in[9];
    const float* msg_w2 = (const float*)d_in[10];
    const float* msg_b2 = (const float*)d_in[11];
    const float* upd_w1 = (const float*)d_in[12];
    const float* upd_b1 = (const float*)d_in[13];
    const float* upd_w2 = (const float*)d_in[14];
    const float* upd_b2 = (const float*)d_in[15];
    const float* out_w1 = (const float*)d_in[16];
    const float* out_b1 = (const float*)d_in[17];
    const float* out_w2 = (const float*)d_in[18];
    const float* out_b2 = (const float*)d_in[19];

    float* w = (float*)d_ws;
    size_t off = 0;
    auto alloc = [&](size_t n) { float* p = w + off; off += n; return p; };
    float* nodein  = alloc((size_t)MROWS * 14);
    float* hf      = alloc((size_t)MROWS * HF);
    float* Au      = alloc((size_t)MROWS * HF);   // also g1 at the end
    float* partial = alloc((size_t)1152 * HF * 2);
    float* musig   = alloc(512);
    unsigned short* hfb  = (unsigned short*)alloc((size_t)MROWS * 64);
    unsigned short* aggb = (unsigned short*)alloc((size_t)MROWS * 64);
    unsigned short* t1b  = (unsigned short*)alloc((size_t)MROWS * 64);
    unsigned short* Abf  = (unsigned short*)alloc((size_t)MROWS * 64);
    unsigned short* Sbf  = (unsigned short*)alloc((size_t)MROWS * 64);
    unsigned short* wT   = (unsigned short*)alloc((size_t)38 * 16384 / 2);
    (void)ws_size; (void)in_sizes; (void)n_in; (void)out_size;

    k_prep<<<38, 256, 0, stream>>>(emb_w2, out_w1, msg_w1, msg_w2, upd_w1, upd_w2, wT);
    k_build<<<(MROWS + 255) / 256, 256, 0, stream>>>(x, pos, nodein);
    // emb layer 1 (K=14, fp32 in, bf16 out)
    k_smallk<14, 1, 1><<<MROWS / 32, 256, 0, stream>>>(nodein, 14, emb_w1, emb_b1, t1b);
    // emb layer 2 (MFMA) -> hf fp32 + hfb bf16
    k_mfma<<<576, 256, 0, stream>>>(t1b, wT + 0 * 16384, nullptr, nullptr,
                                    emb_b2, nullptr, hf, hfb, nullptr, 1);
    for (int l = 0; l < LAYERS; ++l) {
        const unsigned short* wL = wT + (size_t)(2 + 6 * l) * 16384;
        const float* W1 = msg_w1 + (size_t)l * 269 * HF;
        k_smallk<12, 0, 0><<<MROWS / 32, 256, 0, stream>>>(nodein, 14, W1 + 256 * HF,
                                                           nullptr, Au);
        k_as<<<576, 256, 0, stream>>>(hfb, wL + 0 * 16384, wL + 1 * 16384, Au, Abf, Sbf);
        k_agg<<<576, 256, 0, stream>>>(Abf, Sbf, wL + 2 * 16384, msg_b2 + l * HF,
                                       msg_b1 + l * HF, W1 + 268 * HF, aggb);
        k_mfma<<<576, 256, 0, stream>>>(hfb, wL + 3 * 16384, aggb, wL + 4 * 16384,
                                        upd_b1 + l * HF, nullptr, nullptr, t1b,
                                        nullptr, 1);
        k_mfma<<<576, 256, 0, stream>>>(t1b, wL + 5 * 16384, nullptr, nullptr,
                                        upd_b2 + l * HF, hf, hf, nullptr,
                                        partial, 1);
        k_stats<<<256, 256, 0, stream>>>(partial, musig);
        k_norm<<<(MROWS * HF / 4 + 255) / 256, 256, 0, stream>>>(hf, musig, hfb);
    }
    // output head layer 1 -> g1 (reuse Au)
    k_mfma<<<576, 256, 0, stream>>>(hfb, wT + 1 * 16384, nullptr, nullptr,
                                    out_b1, nullptr, Au, nullptr, nullptr, 1);
    k_out2<<<MROWS / 64, 256, 0, stream>>>(Au, out_w2, out_b2, x, (float*)d_out);
}

// Round 6
// 606.503 us; speedup vs baseline: 3.3135x; 1.3379x over previous
//
#include <hip/hip_runtime.h>
#include <math.h>

#define HF 128
#define NB 9216          // nodes per batch (96*96)
#define BB 2
#define MROWS (BB*NB)    // 18432
#define GH 96
#define GW 96
#define LAYERS 6

typedef __attribute__((ext_vector_type(8))) short bf16x8;
typedef __attribute__((ext_vector_type(4))) float f32x4;
typedef unsigned short ushort_t;

#define MFMA16(a, b, c) __builtin_amdgcn_mfma_f32_16x16x32_bf16(a, b, c, 0, 0, 0)

__device__ __forceinline__ float swishf(float x) {
    return __fdividef(x, 1.0f + __expf(-x));
}

// fp32 -> bf16 bits, round-to-nearest-even
__device__ __forceinline__ unsigned short f2b(float f) {
    unsigned u = __float_as_uint(f);
    unsigned r = (u + 0x7fffu + ((u >> 16) & 1u)) >> 16;
    return (unsigned short)r;
}
__device__ __forceinline__ float b2f(unsigned short u) {
    return __uint_as_float((unsigned)u << 16);
}

// ---------------- weight prep: wT[slot][col][k] = bf16(W[k][col]) ----------------
// slots: 0=emb_w2, 1=out_w1, 2+6l+{0..5} = msgW1a, msgW1b, msgW2, updW1a, updW1b, updW2
__global__ void k_prep(const float* __restrict__ embw2, const float* __restrict__ outw1,
                       const float* __restrict__ msgw1, const float* __restrict__ msgw2,
                       const float* __restrict__ updw1, const float* __restrict__ updw2,
                       unsigned short* __restrict__ wT) {
    int s = blockIdx.x;
    const float* src;
    if (s == 0) src = embw2;
    else if (s == 1) src = outw1;
    else {
        int l = (s - 2) / 6, r = (s - 2) % 6;
        if (r == 0)      src = msgw1 + (size_t)l * 269 * HF;
        else if (r == 1) src = msgw1 + (size_t)l * 269 * HF + HF * HF;
        else if (r == 2) src = msgw2 + (size_t)l * HF * HF;
        else if (r == 3) src = updw1 + (size_t)l * 256 * HF;
        else if (r == 4) src = updw1 + (size_t)l * 256 * HF + HF * HF;
        else             src = updw2 + (size_t)l * HF * HF;
    }
    __shared__ float tile[128][133];
    int t = threadIdx.x;
#pragma unroll
    for (int i = 0; i < 64; ++i) {
        int id = i * 256 + t;
        tile[id >> 7][id & 127] = src[id];
    }
    __syncthreads();
    unsigned short* o = wT + (size_t)s * 16384;
#pragma unroll
    for (int i = 0; i < 64; ++i) {
        int id = i * 256 + t;
        int col = id >> 7, k = id & 127;
        o[id] = f2b(tile[k][col]);
    }
}

// ---------------- build nodein [B,N,16] = [u(12) | pos(2) | pad(2)] ----------------
__global__ void k_build(const float* __restrict__ x, const float* __restrict__ pos,
                        float* __restrict__ nodein) {
    int idx = blockIdx.x * 256 + threadIdx.x;
    if (idx >= MROWS) return;
    int b = idx / NB, n = idx - b * NB;
    float* o = nodein + (size_t)idx * 16;
    const float* xb = x + (size_t)b * 12 * NB + n;
#pragma unroll
    for (int k = 0; k < 12; ++k) o[k] = xb[(size_t)k * NB];
    o[12] = pos[2 * n];
    o[13] = pos[2 * n + 1];
    o[14] = 0.0f; o[15] = 0.0f;
}

// ---------------- small-K GEMM: out[M,128] = act(X[M,K] @ W[K,128] (+bias)) ----------------
template<int K, int ACT, int BOUT>
__global__ void k_smallk(const float* __restrict__ X, int ldx,
                         const float* __restrict__ W,
                         const float* __restrict__ bias,
                         void* __restrict__ outv) {
    __shared__ float xs[32][K];
    int row0 = blockIdx.x * 32;
    int t = threadIdx.x;
    for (int idx = t; idx < 32 * K; idx += 256) {
        int r = idx / K, k = idx - r * K;
        xs[r][k] = X[(size_t)(row0 + r) * ldx + k];
    }
    __syncthreads();
    int f = t & 127, rh = t >> 7;
    float wreg[K];
#pragma unroll
    for (int k = 0; k < K; ++k) wreg[k] = W[k * HF + f];
    float bv = bias ? bias[f] : 0.0f;
    for (int r = rh; r < 32; r += 2) {
        float acc = bv;
#pragma unroll
        for (int k = 0; k < K; ++k) acc = fmaf(xs[r][k], wreg[k], acc);
        if (ACT) acc = swishf(acc);
        if (BOUT) ((unsigned short*)outv)[(size_t)(row0 + r) * HF + f] = f2b(acc);
        else      ((float*)outv)[(size_t)(row0 + r) * HF + f] = acc;
    }
}

// ---------------- MFMA GEMM: 1152 blocks, 16 rows/block, 4 col-quarter waves ----------------
// out = [resid +] act( X1@W1 [+ X2@W2] + bias )
__global__ __launch_bounds__(256, 4)
void k_mfma(const unsigned short* __restrict__ X1, const unsigned short* __restrict__ W1,
            const unsigned short* __restrict__ X2, const unsigned short* __restrict__ W2,
            const float* __restrict__ bias, const float* __restrict__ resid,
            float* __restrict__ outF, unsigned short* __restrict__ outB,
            float* __restrict__ partial, int act) {
    int t = threadIdx.x, wave = t >> 6, lane = t & 63, lr = lane & 15, lg = lane >> 4;
    int rt = blockIdx.x * 16;
    int fb = wave * 32;
    f32x4 acc[2];
    acc[0] = (f32x4)0.0f; acc[1] = (f32x4)0.0f;
#pragma unroll
    for (int kc = 0; kc < 4; ++kc) {
        int k0 = kc * 32 + lg * 8;
        bf16x8 a1 = *(const bf16x8*)(X1 + (size_t)(rt + lr) * HF + k0);
        bf16x8 a2;
        if (X2) a2 = *(const bf16x8*)(X2 + (size_t)(rt + lr) * HF + k0);
#pragma unroll
        for (int j = 0; j < 2; ++j) {
            bf16x8 b = *(const bf16x8*)(W1 + (size_t)(fb + j * 16 + lr) * HF + k0);
            acc[j] = MFMA16(a1, b, acc[j]);
            if (X2) {
                bf16x8 b2v = *(const bf16x8*)(W2 + (size_t)(fb + j * 16 + lr) * HF + k0);
                acc[j] = MFMA16(a2, b2v, acc[j]);
            }
        }
    }
#pragma unroll
    for (int j = 0; j < 2; ++j) {
        int f = fb + j * 16 + lr;
        float bv = bias ? bias[f] : 0.0f;
        float s1 = 0.f, s2 = 0.f;
#pragma unroll
        for (int r = 0; r < 4; ++r) {
            int row = rt + lg * 4 + r;
            size_t o = (size_t)row * HF + f;
            float v = acc[j][r] + bv;
            if (act) v = swishf(v);
            if (resid) v += resid[o];
            if (outF) outF[o] = v;
            if (outB) outB[o] = f2b(v);
            s1 += v; s2 += v * v;
        }
        if (partial) {
            s1 += __shfl_xor(s1, 16); s1 += __shfl_xor(s1, 32);
            s2 += __shfl_xor(s2, 16); s2 += __shfl_xor(s2, 32);
            if (lg == 0) {
                float* p = partial + ((size_t)blockIdx.x * HF + f) * 2;
                p[0] = s1; p[1] = s2;
            }
        }
    }
}

// ---------------- A/S projection with fused Au ----------------
// A = bf16(hf@W1a + nodein@W1u) ; S = bf16(hf@W1b - nodein@W1u)
__global__ __launch_bounds__(256, 4)
void k_as(const unsigned short* __restrict__ hfb, const unsigned short* __restrict__ wA,
          const unsigned short* __restrict__ wB, const float* __restrict__ nodein,
          const float* __restrict__ w1u,
          unsigned short* __restrict__ A, unsigned short* __restrict__ S) {
    __shared__ float w1s[12][128];
    int t = threadIdx.x, wave = t >> 6, lane = t & 63, lr = lane & 15, lg = lane >> 4;
    int rt = blockIdx.x * 16;
    int fb = wave * 32;
    for (int i = t; i < 12 * 128; i += 256) w1s[i >> 7][i & 127] = w1u[i];
    f32x4 accA[2], accS[2];
    accA[0] = (f32x4)0.0f; accA[1] = (f32x4)0.0f;
    accS[0] = (f32x4)0.0f; accS[1] = (f32x4)0.0f;
#pragma unroll
    for (int kc = 0; kc < 4; ++kc) {
        int k0 = kc * 32 + lg * 8;
        bf16x8 a = *(const bf16x8*)(hfb + (size_t)(rt + lr) * HF + k0);
#pragma unroll
        for (int j = 0; j < 2; ++j) {
            bf16x8 bA = *(const bf16x8*)(wA + (size_t)(fb + j * 16 + lr) * HF + k0);
            accA[j] = MFMA16(a, bA, accA[j]);
            bf16x8 bS = *(const bf16x8*)(wB + (size_t)(fb + j * 16 + lr) * HF + k0);
            accS[j] = MFMA16(a, bS, accS[j]);
        }
    }
    // nodein rows for this lane (4 rows x 12 feats, float4 aligned via 16-stride)
    float ni[4][12];
#pragma unroll
    for (int r = 0; r < 4; ++r) {
        const float4* np = (const float4*)(nodein + (size_t)(rt + lg * 4 + r) * 16);
        float4 v0 = np[0], v1 = np[1], v2 = np[2];
        ni[r][0] = v0.x; ni[r][1] = v0.y; ni[r][2] = v0.z; ni[r][3] = v0.w;
        ni[r][4] = v1.x; ni[r][5] = v1.y; ni[r][6] = v1.z; ni[r][7] = v1.w;
        ni[r][8] = v2.x; ni[r][9] = v2.y; ni[r][10] = v2.z; ni[r][11] = v2.w;
    }
    __syncthreads();
#pragma unroll
    for (int j = 0; j < 2; ++j) {
        int f = fb + j * 16 + lr;
        float au[4] = {0.f, 0.f, 0.f, 0.f};
#pragma unroll
        for (int k = 0; k < 12; ++k) {
            float wv = w1s[k][f];
#pragma unroll
            for (int r = 0; r < 4; ++r) au[r] = fmaf(ni[r][k], wv, au[r]);
        }
#pragma unroll
        for (int r = 0; r < 4; ++r) {
            size_t o = (size_t)(rt + lg * 4 + r) * HF + f;
            A[o] = f2b(accA[j][r] + au[r]);
            S[o] = f2b(accS[j][r] - au[r]);
        }
    }
}

// ---------------- message + aggregate: z computed once, exchanged via LDS ----------------
// block = 16-row tile; wave kq owns k-quarter [32kq,32kq+32) for z and col-quarter for MFMA.
__global__ __launch_bounds__(256, 4)
void k_agg(const unsigned short* __restrict__ Ab, const unsigned short* __restrict__ Sb,
           const unsigned short* __restrict__ wT2, const float* __restrict__ b2,
           const float* __restrict__ b1, const float* __restrict__ w1d,
           unsigned short* __restrict__ aggb) {
    __shared__ float dsb[3][128];
    __shared__ char exb[8192];     // 2 bufs x 4 kc x 1KB frag slots
    int t = threadIdx.x, kq = t >> 6, lane = t & 63, lr = lane & 15, lg = lane >> 4;
    int bx = blockIdx.x;
    int b = bx / (NB / 16), tile = bx % (NB / 16);
    int rt = tile * 16;                    // 16 | 96 -> single grid row R
    int fb = kq * 32;
    size_t bN = (size_t)b * NB;
    int R = rt / GW, C0 = rt % GW;

    if (t < 128) {
        float bb = b1[t], wd = w1d[t];
        dsb[0][t] = bb;
        dsb[1][t] = fmaf(1.0f / 95.0f, wd, bb);
        dsb[2][t] = fmaf(1.4142135623730951f / 95.0f, wd, bb);
    }
    // W2 fragment cache: this wave's 32 cols x full K (32 VGPR)
    bf16x8 w2f[2][4];
#pragma unroll
    for (int j = 0; j < 2; ++j)
#pragma unroll
        for (int kc = 0; kc < 4; ++kc)
            w2f[j][kc] = *(const bf16x8*)(wT2 + (size_t)(fb + j * 16 + lr) * HF
                                          + kc * 32 + lg * 8);
    // A own k-quarter (8 f32)
    int rowA = rt + lr;
    float Af[8];
    {
        bf16x8 av = *(const bf16x8*)(Ab + (bN + rowA) * HF + kq * 32 + lg * 8);
#pragma unroll
        for (int e = 0; e < 8; ++e) Af[e] = b2f((unsigned short)av[e]);
    }
    float b2r[2] = { b2[fb + lr], b2[fb + 16 + lr] };
    f32x4 agg2[2];
    agg2[0] = (f32x4)0.0f; agg2[1] = (f32x4)0.0f;
    // prefetch S own quarter for offset 0 (dn=-97)
    bf16x8 sv;
    {
        int src = min(max(rowA - 97, 0), NB - 1);
        sv = *(const bf16x8*)(Sb + (bN + src) * HF + kq * 32 + lg * 8);
    }
    int lofs = lane * 16;                  // bijective frag slot within 1KB wave slot
    __syncthreads();   // dsb ready

#pragma unroll 1
    for (int off = 0; off < 9; ++off) {
        int dr = off / 3 - 1, dc = off % 3 - 1;
        int dd = dr * dr + dc * dc;
        bf16x8 cur = sv;
        if (off < 8) {
            int no = off + 1;
            int dnn = (no / 3 - 1) * GW + (no % 3 - 1);
            int src = min(max(rowA + dnn, 0), NB - 1);
            sv = *(const bf16x8*)(Sb + (bN + src) * HF + kq * 32 + lg * 8);
        }
        // z own quarter: 8 evals -> one bf16x8 frag
        const float* dp = &dsb[dd][kq * 32 + lg * 8];
        union { bf16x8 v; unsigned u[4]; } az;
#pragma unroll
        for (int q = 0; q < 4; ++q) {
            float zl = swishf(Af[2 * q]     + b2f((unsigned short)cur[2 * q])     + dp[2 * q]);
            float zh = swishf(Af[2 * q + 1] + b2f((unsigned short)cur[2 * q + 1]) + dp[2 * q + 1]);
            az.u[q] = (unsigned)f2b(zl) | ((unsigned)f2b(zh) << 16);
        }
        char* base = exb + (off & 1) * 4096;
        *(bf16x8*)(base + kq * 1024 + lofs) = az.v;
        __syncthreads();
        f32x4 acc[2];
        acc[0] = (f32x4)0.0f; acc[1] = (f32x4)0.0f;
#pragma unroll
        for (int kc = 0; kc < 4; ++kc) {
            bf16x8 a = *(const bf16x8*)(base + kc * 1024 + lofs);
            acc[0] = MFMA16(a, w2f[0][kc], acc[0]);
            acc[1] = MFMA16(a, w2f[1][kc], acc[1]);
        }
        bool rOK = (unsigned)(R + dr) < (unsigned)GH;
#pragma unroll
        for (int j = 0; j < 2; ++j)
#pragma unroll
            for (int r = 0; r < 4; ++r) {
                int C = C0 + lg * 4 + r;
                if (rOK && (unsigned)(C + dc) < (unsigned)GW)
                    agg2[j][r] += swishf(acc[j][r] + b2r[j]);
            }
    }
    float nr = 1.0f + (R > 0) + (R < GH - 1);
#pragma unroll
    for (int j = 0; j < 2; ++j)
#pragma unroll
        for (int r = 0; r < 4; ++r) {
            int n = rt + lg * 4 + r;
            int C = C0 + lg * 4 + r;
            float nc = 1.0f + (C > 0) + (C < GW - 1);
            aggb[(bN + n) * HF + fb + j * 16 + lr] =
                f2b(__fdividef(agg2[j][r], nr * nc));
        }
}

// ---------------- instance-norm stats reduce: 256 blocks, one (b,f) each ----------------
// partial: [1152 rowtiles][128 f][2]; 576 rowtiles per batch
__global__ void k_stats(const float* __restrict__ partial, float* __restrict__ musig) {
    __shared__ float ss[256], qq[256];
    int bx = blockIdx.x;
    int b = bx >> 7, f = bx & 127;
    int t = threadIdx.x;
    float s = 0.f, q = 0.f;
    for (int i = t; i < 576; i += 256) {
        const float* p = partial + (((size_t)(b * 576 + i)) * HF + f) * 2;
        s += p[0]; q += p[1];
    }
    ss[t] = s; qq[t] = q;
    __syncthreads();
    for (int st = 128; st > 0; st >>= 1) {
        if (t < st) { ss[t] += ss[t + st]; qq[t] += qq[t + st]; }
        __syncthreads();
    }
    if (t == 0) {
        float mu = ss[0] * (1.0f / NB);
        float var = qq[0] * (1.0f / NB) - mu * mu;
        musig[bx] = mu;
        musig[256 + bx] = rsqrtf(var + 1e-5f);
    }
}

__global__ void k_norm(float* __restrict__ hf, const float* __restrict__ musig,
                       unsigned short* __restrict__ hfb) {
    int idx = blockIdx.x * 256 + threadIdx.x;     // per float4
    if (idx >= MROWS * HF / 4) return;
    int b = (idx >= NB * HF / 4) ? 1 : 0;
    int f = (idx * 4) & 127;
    float4 v = ((const float4*)hf)[idx];
    const float* mu = musig + b * 128 + f;
    const float* rs = musig + 256 + b * 128 + f;
    v.x = (v.x - mu[0]) * rs[0];
    v.y = (v.y - mu[1]) * rs[1];
    v.z = (v.z - mu[2]) * rs[2];
    v.w = (v.w - mu[3]) * rs[3];
    ((float4*)hf)[idx] = v;
    uint2 p;
    p.x = (unsigned)f2b(v.x) | ((unsigned)f2b(v.y) << 16);
    p.y = (unsigned)f2b(v.z) | ((unsigned)f2b(v.w) << 16);
    *(uint2*)(hfb + (size_t)idx * 4) = p;
}

// ---------------- output head: diff = g1 @ out_w2 + b2 ; out = x[:,-1] + diff ----------------
__global__ void k_out2(const float* __restrict__ g1, const float* __restrict__ w2,
                       const float* __restrict__ b2, const float* __restrict__ x,
                       float* __restrict__ out) {
    __shared__ float gs[64][HF];
    int row0 = blockIdx.x * 64;
    int t = threadIdx.x;
#pragma unroll
    for (int i = 0; i < 32; ++i) {
        int idx = i * 256 + t;
        int r = idx >> 7, k = idx & 127;
        gs[r][k] = g1[(size_t)(row0 + r) * HF + k];
    }
    __syncthreads();
    if (t < 192) {
        int r = t / 3, c = t - (t / 3) * 3;
        int row = row0 + r;
        int b = row / NB, n = row - b * NB;
        float acc = b2[c];
#pragma unroll 8
        for (int k = 0; k < HF; ++k) acc = fmaf(gs[r][k], w2[k * 3 + c], acc);
        float xv = x[(((size_t)b * 4 + 3) * 3 + c) * NB + n];
        out[((size_t)b * 3 + c) * NB + n] = acc + xv;
    }
}

extern "C" void kernel_launch(void* const* d_in, const int* in_sizes, int n_in,
                              void* d_out, int out_size, void* d_ws, size_t ws_size,
                              hipStream_t stream) {
    const float* x      = (const float*)d_in[0];
    const float* pos    = (const float*)d_in[3];
    const float* emb_w1 = (const float*)d_in[4];
    const float* emb_b1 = (const float*)d_in[5];
    const float* emb_b2 = (const float*)d_in[7];
    const float* msg_w1 = (const float*)d_in[8];
    const float* msg_b1 = (const float*)d_in[9];
    const float* msg_b2 = (const float*)d_in[11];
    const float* upd_b1 = (const float*)d_in[13];
    const float* upd_b2 = (const float*)d_in[15];
    const float* out_b1 = (const float*)d_in[17];
    const float* out_w2 = (const float*)d_in[18];
    const float* out_b2 = (const float*)d_in[19];

    float* w = (float*)d_ws;
    size_t off = 0;
    auto alloc = [&](size_t n) { float* p = w + off; off += n; return p; };
    float* nodein  = alloc((size_t)MROWS * 16);
    float* hf      = alloc((size_t)MROWS * HF);
    float* g1      = alloc((size_t)MROWS * HF);
    float* partial = alloc((size_t)1152 * HF * 2);
    float* musig   = alloc(512);
    unsigned short* hfb  = (unsigned short*)alloc((size_t)MROWS * 64);
    unsigned short* aggb = (unsigned short*)alloc((size_t)MROWS * 64);
    unsigned short* t1b  = (unsigned short*)alloc((size_t)MROWS * 64);
    unsigned short* Abf  = (unsigned short*)alloc((size_t)MROWS * 64);
    unsigned short* Sbf  = (unsigned short*)alloc((size_t)MROWS * 64);
    unsigned short* wT   = (unsigned short*)alloc((size_t)38 * 16384 / 2);
    (void)ws_size; (void)in_sizes; (void)n_in; (void)out_size;

    k_prep<<<38, 256, 0, stream>>>((const float*)d_in[6], (const float*)d_in[16],
                                   msg_w1, (const float*)d_in[10],
                                   (const float*)d_in[12], (const float*)d_in[14], wT);
    k_build<<<(MROWS + 255) / 256, 256, 0, stream>>>(x, pos, nodein);
    // emb layer 1 (K=14, fp32 in, bf16 out)
    k_smallk<14, 1, 1><<<MROWS / 32, 256, 0, stream>>>(nodein, 16, emb_w1, emb_b1, t1b);
    // emb layer 2 (MFMA) -> hf fp32 + hfb bf16
    k_mfma<<<1152, 256, 0, stream>>>(t1b, wT + 0 * 16384, nullptr, nullptr,
                                     emb_b2, nullptr, hf, hfb, nullptr, 1);
    for (int l = 0; l < LAYERS; ++l) {
        const unsigned short* wL = wT + (size_t)(2 + 6 * l) * 16384;
        const float* W1 = msg_w1 + (size_t)l * 269 * HF;
        k_as<<<1152, 256, 0, stream>>>(hfb, wL + 0 * 16384, wL + 1 * 16384,
                                       nodein, W1 + 256 * HF, Abf, Sbf);
        k_agg<<<1152, 256, 0, stream>>>(Abf, Sbf, wL + 2 * 16384, msg_b2 + l * HF,
                                        msg_b1 + l * HF, W1 + 268 * HF, aggb);
        k_mfma<<<1152, 256, 0, stream>>>(hfb, wL + 3 * 16384, aggb, wL + 4 * 16384,
                                         upd_b1 + l * HF, nullptr, nullptr, t1b,
                                         nullptr, 1);
        k_mfma<<<1152, 256, 0, stream>>>(t1b, wL + 5 * 16384, nullptr, nullptr,
                                         upd_b2 + l * HF, hf, hf, nullptr,
                                         partial, 1);
        k_stats<<<256, 256, 0, stream>>>(partial, musig);
        k_norm<<<(MROWS * HF / 4 + 255) / 256, 256, 0, stream>>>(hf, musig, hfb);
    }
    // output head layer 1 -> g1
    k_mfma<<<1152, 256, 0, stream>>>(hfb, wT + 1 * 16384, nullptr, nullptr,
                                     out_b1, nullptr, g1, nullptr, nullptr, 1);
    k_out2<<<MROWS / 64, 256, 0, stream>>>(g1, out_w2, out_b2, x, (float*)d_out);
}

// Round 8
// 550.148 us; speedup vs baseline: 3.6529x; 1.1024x over previous
//
#include <hip/hip_runtime.h>
#include <math.h>

#define HF 128
#define NB 9216          // nodes per batch (96*96)
#define BB 2
#define MROWS (BB*NB)    // 18432
#define GH 96
#define GW 96
#define LAYERS 6

typedef __attribute__((ext_vector_type(8))) short bf16x8;
typedef __attribute__((ext_vector_type(4))) float f32x4;

#define MFMA16(a, b, c) __builtin_amdgcn_mfma_f32_16x16x32_bf16(a, b, c, 0, 0, 0)

__device__ __forceinline__ float swishf(float x) {
    return __fdividef(x, 1.0f + __expf(-x));
}

// fp32 -> bf16 bits, round-to-nearest-even
__device__ __forceinline__ unsigned short f2b(float f) {
    unsigned u = __float_as_uint(f);
    unsigned r = (u + 0x7fffu + ((u >> 16) & 1u)) >> 16;
    return (unsigned short)r;
}
__device__ __forceinline__ float b2f(unsigned short u) {
    return __uint_as_float((unsigned)u << 16);
}

// ---------------- weight prep: wT[slot][col][k] = bf16(W[k][col]) ----------------
// slots: 0=emb_w2, 1=out_w1, 2+6l+{0..5} = msgW1a, msgW1b, msgW2, updW1a, updW1b, updW2
__global__ void k_prep(const float* __restrict__ embw2, const float* __restrict__ outw1,
                       const float* __restrict__ msgw1, const float* __restrict__ msgw2,
                       const float* __restrict__ updw1, const float* __restrict__ updw2,
                       unsigned short* __restrict__ wT) {
    int s = blockIdx.x;
    const float* src;
    if (s == 0) src = embw2;
    else if (s == 1) src = outw1;
    else {
        int l = (s - 2) / 6, r = (s - 2) % 6;
        if (r == 0)      src = msgw1 + (size_t)l * 269 * HF;
        else if (r == 1) src = msgw1 + (size_t)l * 269 * HF + HF * HF;
        else if (r == 2) src = msgw2 + (size_t)l * HF * HF;
        else if (r == 3) src = updw1 + (size_t)l * 256 * HF;
        else if (r == 4) src = updw1 + (size_t)l * 256 * HF + HF * HF;
        else             src = updw2 + (size_t)l * HF * HF;
    }
    __shared__ float tile[128][133];
    int t = threadIdx.x;
#pragma unroll
    for (int i = 0; i < 64; ++i) {
        int id = i * 256 + t;
        tile[id >> 7][id & 127] = src[id];
    }
    __syncthreads();
    unsigned short* o = wT + (size_t)s * 16384;
#pragma unroll
    for (int i = 0; i < 64; ++i) {
        int id = i * 256 + t;
        int col = id >> 7, k = id & 127;
        o[id] = f2b(tile[k][col]);
    }
}

// ---------------- build nodein [B,N,16] = [u(12) | pos(2) | pad(2)] ----------------
__global__ void k_build(const float* __restrict__ x, const float* __restrict__ pos,
                        float* __restrict__ nodein) {
    int idx = blockIdx.x * 256 + threadIdx.x;
    if (idx >= MROWS) return;
    int b = idx / NB, n = idx - b * NB;
    float* o = nodein + (size_t)idx * 16;
    const float* xb = x + (size_t)b * 12 * NB + n;
#pragma unroll
    for (int k = 0; k < 12; ++k) o[k] = xb[(size_t)k * NB];
    o[12] = pos[2 * n];
    o[13] = pos[2 * n + 1];
    o[14] = 0.0f; o[15] = 0.0f;
}

// ---------------- fused embedding: t1 = swish(nodein@W1+b1); hf = swish(t1@W2+b2) ----------------
__global__ __launch_bounds__(256, 4)
void k_emb(const float* __restrict__ nodein, const float* __restrict__ w1,
           const float* __restrict__ b1, const unsigned short* __restrict__ wT2,
           const float* __restrict__ b2,
           float* __restrict__ hf, unsigned short* __restrict__ hfb) {
    __shared__ float xs[16][14];
    __shared__ char t1s[4096];
    int t = threadIdx.x;
    int rt = blockIdx.x * 16;
    if (t < 224) {
        int r = t / 14, k = t - r * 14;
        xs[r][k] = nodein[(size_t)(rt + r) * 16 + k];
    }
    __syncthreads();
    // emb layer 1: thread handles col f, rows rblk*8..+8
    {
        int f = t & 127, rblk = t >> 7;
        float wreg[14];
#pragma unroll
        for (int k = 0; k < 14; ++k) wreg[k] = w1[k * HF + f];
        float bv = b1[f];
#pragma unroll
        for (int i = 0; i < 8; ++i) {
            int row = rblk * 8 + i;
            float acc = bv;
#pragma unroll
            for (int k = 0; k < 14; ++k) acc = fmaf(xs[row][k], wreg[k], acc);
            int addr = (row * 256 + f * 2) ^ ((row & 7) << 4);
            *(unsigned short*)(t1s + addr) = f2b(swishf(acc));
        }
    }
    __syncthreads();
    // emb layer 2 (MFMA)
    int wave = t >> 6, lane = t & 63, lr = lane & 15, lg = lane >> 4;
    int fb = wave * 32;
    f32x4 acc[2];
    acc[0] = (f32x4)0.0f; acc[1] = (f32x4)0.0f;
#pragma unroll
    for (int kc = 0; kc < 4; ++kc) {
        int k0 = kc * 32 + lg * 8;
        bf16x8 a = *(const bf16x8*)(t1s + ((lr * 256 + k0 * 2) ^ ((lr & 7) << 4)));
#pragma unroll
        for (int j = 0; j < 2; ++j) {
            bf16x8 b = *(const bf16x8*)(wT2 + (size_t)(fb + j * 16 + lr) * HF + k0);
            acc[j] = MFMA16(a, b, acc[j]);
        }
    }
#pragma unroll
    for (int j = 0; j < 2; ++j) {
        int f = fb + j * 16 + lr;
        float bv = b2[f];
#pragma unroll
        for (int r = 0; r < 4; ++r) {
            size_t o = (size_t)(rt + lg * 4 + r) * HF + f;
            float v = swishf(acc[j][r] + bv);
            hf[o] = v;
            hfb[o] = f2b(v);
        }
    }
}

// ---------------- A/S projection with fused Au ----------------
// A = bf16(hf@W1a + nodein@W1u) ; S = bf16(hf@W1b - nodein@W1u)
__global__ __launch_bounds__(256, 4)
void k_as(const unsigned short* __restrict__ hfb, const unsigned short* __restrict__ wA,
          const unsigned short* __restrict__ wB, const float* __restrict__ nodein,
          const float* __restrict__ w1u,
          unsigned short* __restrict__ A, unsigned short* __restrict__ S) {
    __shared__ float w1s[12][128];
    int t = threadIdx.x, wave = t >> 6, lane = t & 63, lr = lane & 15, lg = lane >> 4;
    int rt = blockIdx.x * 16;
    int fb = wave * 32;
    for (int i = t; i < 12 * 128; i += 256) w1s[i >> 7][i & 127] = w1u[i];
    f32x4 accA[2], accS[2];
    accA[0] = (f32x4)0.0f; accA[1] = (f32x4)0.0f;
    accS[0] = (f32x4)0.0f; accS[1] = (f32x4)0.0f;
#pragma unroll
    for (int kc = 0; kc < 4; ++kc) {
        int k0 = kc * 32 + lg * 8;
        bf16x8 a = *(const bf16x8*)(hfb + (size_t)(rt + lr) * HF + k0);
#pragma unroll
        for (int j = 0; j < 2; ++j) {
            bf16x8 bA = *(const bf16x8*)(wA + (size_t)(fb + j * 16 + lr) * HF + k0);
            accA[j] = MFMA16(a, bA, accA[j]);
            bf16x8 bS = *(const bf16x8*)(wB + (size_t)(fb + j * 16 + lr) * HF + k0);
            accS[j] = MFMA16(a, bS, accS[j]);
        }
    }
    // nodein rows for this lane (4 rows x 12 feats, float4 aligned via 16-stride)
    float ni[4][12];
#pragma unroll
    for (int r = 0; r < 4; ++r) {
        const float4* np = (const float4*)(nodein + (size_t)(rt + lg * 4 + r) * 16);
        float4 v0 = np[0], v1 = np[1], v2 = np[2];
        ni[r][0] = v0.x; ni[r][1] = v0.y; ni[r][2] = v0.z; ni[r][3] = v0.w;
        ni[r][4] = v1.x; ni[r][5] = v1.y; ni[r][6] = v1.z; ni[r][7] = v1.w;
        ni[r][8] = v2.x; ni[r][9] = v2.y; ni[r][10] = v2.z; ni[r][11] = v2.w;
    }
    __syncthreads();
#pragma unroll
    for (int j = 0; j < 2; ++j) {
        int f = fb + j * 16 + lr;
        float au[4] = {0.f, 0.f, 0.f, 0.f};
#pragma unroll
        for (int k = 0; k < 12; ++k) {
            float wv = w1s[k][f];
#pragma unroll
            for (int r = 0; r < 4; ++r) au[r] = fmaf(ni[r][k], wv, au[r]);
        }
#pragma unroll
        for (int r = 0; r < 4; ++r) {
            size_t o = (size_t)(rt + lg * 4 + r) * HF + f;
            A[o] = f2b(accA[j][r] + au[r]);
            S[o] = f2b(accS[j][r] - au[r]);
        }
    }
}

// ---------------- message + aggregate: phase1 all-z -> 1 barrier -> phase2 all-MFMA ----------------
__global__ __launch_bounds__(256, 4)
void k_agg(const unsigned short* __restrict__ Ab, const unsigned short* __restrict__ Sb,
           const unsigned short* __restrict__ wT2, const float* __restrict__ b2,
           const float* __restrict__ b1, const float* __restrict__ w1d,
           unsigned short* __restrict__ aggb) {
    __shared__ float dsb[3][128];
    __shared__ char exb[9 * 4096];       // z frags for all 9 offsets
    int t = threadIdx.x, kq = t >> 6, lane = t & 63, lr = lane & 15, lg = lane >> 4;
    int bx = blockIdx.x;
    int b = bx / (NB / 16), tile = bx % (NB / 16);
    int rt = tile * 16;                  // 16 | 96 -> single grid row R
    int fb = kq * 32;
    size_t bN = (size_t)b * NB;
    int R = rt / GW, C0 = rt % GW;

    if (t < 128) {
        float bb = b1[t], wd = w1d[t];
        dsb[0][t] = bb;
        dsb[1][t] = fmaf(1.0f / 95.0f, wd, bb);
        dsb[2][t] = fmaf(1.4142135623730951f / 95.0f, wd, bb);
    }
    // W2 fragment cache: this wave's 32 cols x full K (32 VGPR)
    bf16x8 w2f[2][4];
#pragma unroll
    for (int j = 0; j < 2; ++j)
#pragma unroll
        for (int kc = 0; kc < 4; ++kc)
            w2f[j][kc] = *(const bf16x8*)(wT2 + (size_t)(fb + j * 16 + lr) * HF
                                          + kc * 32 + lg * 8);
    // A own k-quarter (8 f32)
    int rowA = rt + lr;
    float Af[8];
    {
        bf16x8 av = *(const bf16x8*)(Ab + (bN + rowA) * HF + kq * 32 + lg * 8);
#pragma unroll
        for (int e = 0; e < 8; ++e) Af[e] = b2f((unsigned short)av[e]);
    }
    float b2r[2] = { b2[fb + lr], b2[fb + 16 + lr] };
    int lofs = lane * 16;
    __syncthreads();   // dsb ready

    // ---- phase 1: z for all 9 offsets (own k-quarter), prefetch depth 1 ----
    bf16x8 sv;
    {
        int src = min(max(rowA - 97, 0), NB - 1);
        sv = *(const bf16x8*)(Sb + (bN + src) * HF + kq * 32 + lg * 8);
    }
#pragma unroll
    for (int off = 0; off < 9; ++off) {
        int dr = off / 3 - 1, dc = off % 3 - 1;
        int dd = dr * dr + dc * dc;
        bf16x8 cur = sv;
        if (off < 8) {
            int no = off + 1;
            int dnn = (no / 3 - 1) * GW + (no % 3 - 1);
            int src = min(max(rowA + dnn, 0), NB - 1);
            sv = *(const bf16x8*)(Sb + (bN + src) * HF + kq * 32 + lg * 8);
        }
        const float* dp = &dsb[dd][kq * 32 + lg * 8];
        union { bf16x8 v; unsigned u[4]; } az;
#pragma unroll
        for (int q = 0; q < 4; ++q) {
            float zl = swishf(Af[2 * q]     + b2f((unsigned short)cur[2 * q])     + dp[2 * q]);
            float zh = swishf(Af[2 * q + 1] + b2f((unsigned short)cur[2 * q + 1]) + dp[2 * q + 1]);
            az.u[q] = (unsigned)f2b(zl) | ((unsigned)f2b(zh) << 16);
        }
        *(bf16x8*)(exb + off * 4096 + kq * 1024 + lofs) = az.v;
    }
    __syncthreads();

    // ---- phase 2: barrier-free MFMA + epilogue over all 9 offsets ----
    f32x4 agg2[2];
    agg2[0] = (f32x4)0.0f; agg2[1] = (f32x4)0.0f;
#pragma unroll
    for (int off = 0; off < 9; ++off) {
        int dr = off / 3 - 1, dc = off % 3 - 1;
        f32x4 acc[2];
        acc[0] = (f32x4)0.0f; acc[1] = (f32x4)0.0f;
#pragma unroll
        for (int kc = 0; kc < 4; ++kc) {
            bf16x8 a = *(const bf16x8*)(exb + off * 4096 + kc * 1024 + lofs);
            acc[0] = MFMA16(a, w2f[0][kc], acc[0]);
            acc[1] = MFMA16(a, w2f[1][kc], acc[1]);
        }
        bool rOK = (unsigned)(R + dr) < (unsigned)GH;
#pragma unroll
        for (int j = 0; j < 2; ++j)
#pragma unroll
            for (int r = 0; r < 4; ++r) {
                int C = C0 + lg * 4 + r;
                if (rOK && (unsigned)(C + dc) < (unsigned)GW)
                    agg2[j][r] += swishf(acc[j][r] + b2r[j]);
            }
    }
    float nr = 1.0f + (R > 0) + (R < GH - 1);
#pragma unroll
    for (int j = 0; j < 2; ++j)
#pragma unroll
        for (int r = 0; r < 4; ++r) {
            int n = rt + lg * 4 + r;
            int C = C0 + lg * 4 + r;
            float nc = 1.0f + (C > 0) + (C < GW - 1);
            aggb[(bN + n) * HF + fb + j * 16 + lr] =
                f2b(__fdividef(agg2[j][r], nr * nc));
        }
}

// ---------------- fused update MLP: t1 = swish(hfb@W1a + aggb@W1b + b1);
// v = swish(t1@W2 + b2) + hf(resid); hf,hfb <- v; partial stats ----------------
__global__ __launch_bounds__(256, 4)
void k_upd(const unsigned short* __restrict__ hfb_in, const unsigned short* __restrict__ aggb,
           const unsigned short* __restrict__ w1a, const unsigned short* __restrict__ w1b,
           const unsigned short* __restrict__ w2, const float* __restrict__ b1v,
           const float* __restrict__ b2v, float* __restrict__ hf,
           unsigned short* __restrict__ hfb_out, float* __restrict__ partial) {
    __shared__ char t1s[4096];
    int t = threadIdx.x, wave = t >> 6, lane = t & 63, lr = lane & 15, lg = lane >> 4;
    int rt = blockIdx.x * 16;
    int fb = wave * 32;
    // GEMM1 (dual input)
    f32x4 acc[2];
    acc[0] = (f32x4)0.0f; acc[1] = (f32x4)0.0f;
#pragma unroll
    for (int kc = 0; kc < 4; ++kc) {
        int k0 = kc * 32 + lg * 8;
        bf16x8 a1 = *(const bf16x8*)(hfb_in + (size_t)(rt + lr) * HF + k0);
        bf16x8 a2 = *(const bf16x8*)(aggb + (size_t)(rt + lr) * HF + k0);
#pragma unroll
        for (int j = 0; j < 2; ++j) {
            bf16x8 bA = *(const bf16x8*)(w1a + (size_t)(fb + j * 16 + lr) * HF + k0);
            acc[j] = MFMA16(a1, bA, acc[j]);
            bf16x8 bB = *(const bf16x8*)(w1b + (size_t)(fb + j * 16 + lr) * HF + k0);
            acc[j] = MFMA16(a2, bB, acc[j]);
        }
    }
    // t1 = swish(acc + b1) -> swizzled LDS (scalar b16 writes)
#pragma unroll
    for (int j = 0; j < 2; ++j) {
        int col = fb + j * 16 + lr;
        float bv = b1v[col];
#pragma unroll
        for (int r = 0; r < 4; ++r) {
            int row = lg * 4 + r;
            int addr = (row * 256 + col * 2) ^ ((row & 7) << 4);
            *(unsigned short*)(t1s + addr) = f2b(swishf(acc[j][r] + bv));
        }
    }
    __syncthreads();
    // GEMM2
    f32x4 acc2[2];
    acc2[0] = (f32x4)0.0f; acc2[1] = (f32x4)0.0f;
#pragma unroll
    for (int kc = 0; kc < 4; ++kc) {
        int k0 = kc * 32 + lg * 8;
        bf16x8 a = *(const bf16x8*)(t1s + ((lr * 256 + k0 * 2) ^ ((lr & 7) << 4)));
#pragma unroll
        for (int j = 0; j < 2; ++j) {
            bf16x8 b = *(const bf16x8*)(w2 + (size_t)(fb + j * 16 + lr) * HF + k0);
            acc2[j] = MFMA16(a, b, acc2[j]);
        }
    }
#pragma unroll
    for (int j = 0; j < 2; ++j) {
        int f = fb + j * 16 + lr;
        float bv = b2v[f];
        float s1 = 0.f, s2 = 0.f;
#pragma unroll
        for (int r = 0; r < 4; ++r) {
            size_t o = (size_t)(rt + lg * 4 + r) * HF + f;
            float v = swishf(acc2[j][r] + bv) + hf[o];
            hf[o] = v;
            hfb_out[o] = f2b(v);
            s1 += v; s2 += v * v;
        }
        s1 += __shfl_xor(s1, 16); s1 += __shfl_xor(s1, 32);
        s2 += __shfl_xor(s2, 16); s2 += __shfl_xor(s2, 32);
        if (lg == 0) {
            float* p = partial + ((size_t)blockIdx.x * HF + f) * 2;
            p[0] = s1; p[1] = s2;
        }
    }
}

// ---------------- instance-norm stats reduce: 256 blocks, one (b,f) each ----------------
__global__ void k_stats(const float* __restrict__ partial, float* __restrict__ musig) {
    __shared__ float ss[256], qq[256];
    int bx = blockIdx.x;
    int b = bx >> 7, f = bx & 127;
    int t = threadIdx.x;
    float s = 0.f, q = 0.f;
    for (int i = t; i < 576; i += 256) {
        const float* p = partial + (((size_t)(b * 576 + i)) * HF + f) * 2;
        s += p[0]; q += p[1];
    }
    ss[t] = s; qq[t] = q;
    __syncthreads();
    for (int st = 128; st > 0; st >>= 1) {
        if (t < st) { ss[t] += ss[t + st]; qq[t] += qq[t + st]; }
        __syncthreads();
    }
    if (t == 0) {
        float mu = ss[0] * (1.0f / NB);
        float var = qq[0] * (1.0f / NB) - mu * mu;
        musig[bx] = mu;
        musig[256 + bx] = rsqrtf(var + 1e-5f);
    }
}

__global__ void k_norm(float* __restrict__ hf, const float* __restrict__ musig,
                       unsigned short* __restrict__ hfb) {
    int idx = blockIdx.x * 256 + threadIdx.x;     // per float4
    if (idx >= MROWS * HF / 4) return;
    int b = (idx >= NB * HF / 4) ? 1 : 0;
    int f = (idx * 4) & 127;
    float4 v = ((const float4*)hf)[idx];
    const float* mu = musig + b * 128 + f;
    const float* rs = musig + 256 + b * 128 + f;
    v.x = (v.x - mu[0]) * rs[0];
    v.y = (v.y - mu[1]) * rs[1];
    v.z = (v.z - mu[2]) * rs[2];
    v.w = (v.w - mu[3]) * rs[3];
    ((float4*)hf)[idx] = v;
    uint2 p;
    p.x = (unsigned)f2b(v.x) | ((unsigned)f2b(v.y) << 16);
    p.y = (unsigned)f2b(v.z) | ((unsigned)f2b(v.w) << 16);
    *(uint2*)(hfb + (size_t)idx * 4) = p;
}

// ---------------- fused output head: g1 = swish(hfb@W1+b1); out = x[:,-1] + g1@W2 + b2 ----------------
__global__ __launch_bounds__(256, 4)
void k_out(const unsigned short* __restrict__ hfb, const unsigned short* __restrict__ wT1,
           const float* __restrict__ b1, const float* __restrict__ w2,
           const float* __restrict__ b2, const float* __restrict__ x,
           float* __restrict__ out) {
    __shared__ float g1s[16][132];
    __shared__ float w2s[384];
    int t = threadIdx.x, wave = t >> 6, lane = t & 63, lr = lane & 15, lg = lane >> 4;
    int rt = blockIdx.x * 16;
    int fb = wave * 32;
    for (int i = t; i < 384; i += 256) w2s[i] = w2[i];
    f32x4 acc[2];
    acc[0] = (f32x4)0.0f; acc[1] = (f32x4)0.0f;
#pragma unroll
    for (int kc = 0; kc < 4; ++kc) {
        int k0 = kc * 32 + lg * 8;
        bf16x8 a = *(const bf16x8*)(hfb + (size_t)(rt + lr) * HF + k0);
#pragma unroll
        for (int j = 0; j < 2; ++j) {
            bf16x8 b = *(const bf16x8*)(wT1 + (size_t)(fb + j * 16 + lr) * HF + k0);
            acc[j] = MFMA16(a, b, acc[j]);
        }
    }
#pragma unroll
    for (int j = 0; j < 2; ++j) {
        int f = fb + j * 16 + lr;
        float bv = b1[f];
#pragma unroll
        for (int r = 0; r < 4; ++r)
            g1s[lg * 4 + r][f] = swishf(acc[j][r] + bv);
    }
    __syncthreads();
    if (t < 48) {
        int r = t / 3, c = t - (t / 3) * 3;
        int row = rt + r;
        int b = row / NB, n = row - b * NB;
        float a = b2[c];
#pragma unroll 8
        for (int k = 0; k < HF; ++k) a = fmaf(g1s[r][k], w2s[k * 3 + c], a);
        float xv = x[(((size_t)b * 4 + 3) * 3 + c) * NB + n];
        out[((size_t)b * 3 + c) * NB + n] = a + xv;
    }
}

extern "C" void kernel_launch(void* const* d_in, const int* in_sizes, int n_in,
                              void* d_out, int out_size, void* d_ws, size_t ws_size,
                              hipStream_t stream) {
    const float* x      = (const float*)d_in[0];
    const float* pos    = (const float*)d_in[3];
    const float* emb_w1 = (const float*)d_in[4];
    const float* emb_b1 = (const float*)d_in[5];
    const float* emb_b2 = (const float*)d_in[7];
    const float* msg_w1 = (const float*)d_in[8];
    const float* msg_b1 = (const float*)d_in[9];
    const float* msg_b2 = (const float*)d_in[11];
    const float* upd_b1 = (const float*)d_in[13];
    const float* upd_b2 = (const float*)d_in[15];
    const float* out_b1 = (const float*)d_in[17];
    const float* out_w2 = (const float*)d_in[18];
    const float* out_b2 = (const float*)d_in[19];

    float* w = (float*)d_ws;
    size_t off = 0;
    auto alloc = [&](size_t n) { float* p = w + off; off += n; return p; };
    float* nodein  = alloc((size_t)MROWS * 16);
    float* hf      = alloc((size_t)MROWS * HF);
    float* partial = alloc((size_t)1152 * HF * 2);
    float* musig   = alloc(512);
    unsigned short* hfb  = (unsigned short*)alloc((size_t)MROWS * 64);
    unsigned short* aggb = (unsigned short*)alloc((size_t)MROWS * 64);
    unsigned short* Abf  = (unsigned short*)alloc((size_t)MROWS * 64);
    unsigned short* Sbf  = (unsigned short*)alloc((size_t)MROWS * 64);
    unsigned short* wT   = (unsigned short*)alloc((size_t)38 * 16384 / 2);
    (void)ws_size; (void)in_sizes; (void)n_in; (void)out_size;

    k_prep<<<38, 256, 0, stream>>>((const float*)d_in[6], (const float*)d_in[16],
                                   msg_w1, (const float*)d_in[10],
                                   (const float*)d_in[12], (const float*)d_in[14], wT);
    k_build<<<(MROWS + 255) / 256, 256, 0, stream>>>(x, pos, nodein);
    k_emb<<<1152, 256, 0, stream>>>(nodein, emb_w1, emb_b1, wT + 0 * 16384, emb_b2,
                                    hf, hfb);
    for (int l = 0; l < LAYERS; ++l) {
        const unsigned short* wL = wT + (size_t)(2 + 6 * l) * 16384;
        const float* W1 = msg_w1 + (size_t)l * 269 * HF;
        k_as<<<1152, 256, 0, stream>>>(hfb, wL + 0 * 16384, wL + 1 * 16384,
                                       nodein, W1 + 256 * HF, Abf, Sbf);
        k_agg<<<1152, 256, 0, stream>>>(Abf, Sbf, wL + 2 * 16384, msg_b2 + l * HF,
                                        msg_b1 + l * HF, W1 + 268 * HF, aggb);
        k_upd<<<1152, 256, 0, stream>>>(hfb, aggb, wL + 3 * 16384, wL + 4 * 16384,
                                        wL + 5 * 16384, upd_b1 + l * HF,
                                        upd_b2 + l * HF, hf, hfb, partial);
        k_stats<<<256, 256, 0, stream>>>(partial, musig);
        k_norm<<<(MROWS * HF / 4 + 255) / 256, 256, 0, stream>>>(hf, musig, hfb);
    }
    k_out<<<1152, 256, 0, stream>>>(hfb, wT + 1 * 16384, out_b1, out_w2, out_b2,
                                    x, (float*)d_out);
}

// Round 9
// 522.766 us; speedup vs baseline: 3.8443x; 1.0524x over previous
//
#include <hip/hip_runtime.h>
#include <math.h>

#define HF 128
#define NB 9216          // nodes per batch (96*96)
#define BB 2
#define MROWS (BB*NB)    // 18432
#define GH 96
#define GW 96
#define LAYERS 6

typedef __attribute__((ext_vector_type(8))) short bf16x8;
typedef __attribute__((ext_vector_type(4))) float f32x4;

#define MFMA16(a, b, c) __builtin_amdgcn_mfma_f32_16x16x32_bf16(a, b, c, 0, 0, 0)

__device__ __forceinline__ float swishf(float x) {
    return __fdividef(x, 1.0f + __expf(-x));
}

// fp32 -> bf16 bits, round-to-nearest-even
__device__ __forceinline__ unsigned short f2b(float f) {
    unsigned u = __float_as_uint(f);
    unsigned r = (u + 0x7fffu + ((u >> 16) & 1u)) >> 16;
    return (unsigned short)r;
}
__device__ __forceinline__ float b2f(unsigned short u) {
    return __uint_as_float((unsigned)u << 16);
}

// normalize 8 hf values -> bf16x8 fragment
__device__ __forceinline__ bf16x8 norm_frag(const float* __restrict__ hp,
                                            const float* __restrict__ mus,
                                            const float* __restrict__ rss, int k0) {
    float4 h0 = *(const float4*)hp;
    float4 h1 = *(const float4*)(hp + 4);
    float4 m0 = *(const float4*)&mus[k0];
    float4 m1 = *(const float4*)&mus[k0 + 4];
    float4 r0 = *(const float4*)&rss[k0];
    float4 r1 = *(const float4*)&rss[k0 + 4];
    union { bf16x8 v; unsigned u[4]; } az;
    float a0 = (h0.x - m0.x) * r0.x, a1 = (h0.y - m0.y) * r0.y;
    az.u[0] = (unsigned)f2b(a0) | ((unsigned)f2b(a1) << 16);
    float a2 = (h0.z - m0.z) * r0.z, a3 = (h0.w - m0.w) * r0.w;
    az.u[1] = (unsigned)f2b(a2) | ((unsigned)f2b(a3) << 16);
    float a4 = (h1.x - m1.x) * r1.x, a5 = (h1.y - m1.y) * r1.y;
    az.u[2] = (unsigned)f2b(a4) | ((unsigned)f2b(a5) << 16);
    float a6 = (h1.z - m1.z) * r1.z, a7 = (h1.w - m1.w) * r1.w;
    az.u[3] = (unsigned)f2b(a6) | ((unsigned)f2b(a7) << 16);
    return az.v;
}

// ---------------- weight prep: wT[slot][col][k] = bf16(W[k][col]) ----------------
// slots: 0=emb_w2, 1=out_w1, 2+6l+{0..5} = msgW1a, msgW1b, msgW2, updW1a, updW1b, updW2
__global__ void k_prep(const float* __restrict__ embw2, const float* __restrict__ outw1,
                       const float* __restrict__ msgw1, const float* __restrict__ msgw2,
                       const float* __restrict__ updw1, const float* __restrict__ updw2,
                       unsigned short* __restrict__ wT) {
    int s = blockIdx.x;
    const float* src;
    if (s == 0) src = embw2;
    else if (s == 1) src = outw1;
    else {
        int l = (s - 2) / 6, r = (s - 2) % 6;
        if (r == 0)      src = msgw1 + (size_t)l * 269 * HF;
        else if (r == 1) src = msgw1 + (size_t)l * 269 * HF + HF * HF;
        else if (r == 2) src = msgw2 + (size_t)l * HF * HF;
        else if (r == 3) src = updw1 + (size_t)l * 256 * HF;
        else if (r == 4) src = updw1 + (size_t)l * 256 * HF + HF * HF;
        else             src = updw2 + (size_t)l * HF * HF;
    }
    __shared__ float tile[128][133];
    int t = threadIdx.x;
#pragma unroll
    for (int i = 0; i < 64; ++i) {
        int id = i * 256 + t;
        tile[id >> 7][id & 127] = src[id];
    }
    __syncthreads();
    unsigned short* o = wT + (size_t)s * 16384;
#pragma unroll
    for (int i = 0; i < 64; ++i) {
        int id = i * 256 + t;
        int col = id >> 7, k = id & 127;
        o[id] = f2b(tile[k][col]);
    }
}

// ---------------- build nodein [B,N,16]; init musig to identity ----------------
__global__ void k_build(const float* __restrict__ x, const float* __restrict__ pos,
                        float* __restrict__ nodein, float* __restrict__ musig) {
    int t = threadIdx.x;
    int idx = blockIdx.x * 256 + t;
    if (blockIdx.x == 0 && t < 256) {
        musig[t] = 0.0f;          // mu = 0
        musig[256 + t] = 1.0f;    // rsig = 1
    }
    if (idx >= MROWS) return;
    int b = idx / NB, n = idx - b * NB;
    float* o = nodein + (size_t)idx * 16;
    const float* xb = x + (size_t)b * 12 * NB + n;
#pragma unroll
    for (int k = 0; k < 12; ++k) o[k] = xb[(size_t)k * NB];
    o[12] = pos[2 * n];
    o[13] = pos[2 * n + 1];
    o[14] = 0.0f; o[15] = 0.0f;
}

// ---------------- fused embedding: t1 = swish(nodein@W1+b1); hf = swish(t1@W2+b2) ----------------
__global__ __launch_bounds__(256, 4)
void k_emb(const float* __restrict__ nodein, const float* __restrict__ w1,
           const float* __restrict__ b1, const unsigned short* __restrict__ wT2,
           const float* __restrict__ b2, float* __restrict__ hf) {
    __shared__ float xs[16][14];
    __shared__ char t1s[4096];
    int t = threadIdx.x;
    int rt = blockIdx.x * 16;
    if (t < 224) {
        int r = t / 14, k = t - r * 14;
        xs[r][k] = nodein[(size_t)(rt + r) * 16 + k];
    }
    __syncthreads();
    {
        int f = t & 127, rblk = t >> 7;
        float wreg[14];
#pragma unroll
        for (int k = 0; k < 14; ++k) wreg[k] = w1[k * HF + f];
        float bv = b1[f];
#pragma unroll
        for (int i = 0; i < 8; ++i) {
            int row = rblk * 8 + i;
            float acc = bv;
#pragma unroll
            for (int k = 0; k < 14; ++k) acc = fmaf(xs[row][k], wreg[k], acc);
            int addr = (row * 256 + f * 2) ^ ((row & 7) << 4);
            *(unsigned short*)(t1s + addr) = f2b(swishf(acc));
        }
    }
    __syncthreads();
    int wave = t >> 6, lane = t & 63, lr = lane & 15, lg = lane >> 4;
    int fb = wave * 32;
    f32x4 acc[2];
    acc[0] = (f32x4)0.0f; acc[1] = (f32x4)0.0f;
#pragma unroll
    for (int kc = 0; kc < 4; ++kc) {
        int k0 = kc * 32 + lg * 8;
        bf16x8 a = *(const bf16x8*)(t1s + ((lr * 256 + k0 * 2) ^ ((lr & 7) << 4)));
#pragma unroll
        for (int j = 0; j < 2; ++j) {
            bf16x8 b = *(const bf16x8*)(wT2 + (size_t)(fb + j * 16 + lr) * HF + k0);
            acc[j] = MFMA16(a, b, acc[j]);
        }
    }
#pragma unroll
    for (int j = 0; j < 2; ++j) {
        int f = fb + j * 16 + lr;
        float bv = b2[f];
#pragma unroll
        for (int r = 0; r < 4; ++r) {
            size_t o = (size_t)(rt + lg * 4 + r) * HF + f;
            hf[o] = swishf(acc[j][r] + bv);
        }
    }
}

// ---------------- A/S projection (norm-on-read) with fused Au ----------------
// A = bf16(norm(hf)@W1a + nodein@W1u) ; S = bf16(norm(hf)@W1b - nodein@W1u)
__global__ __launch_bounds__(256, 4)
void k_as(const float* __restrict__ hf, const float* __restrict__ musig,
          const unsigned short* __restrict__ wA, const unsigned short* __restrict__ wB,
          const float* __restrict__ nodein, const float* __restrict__ w1u,
          unsigned short* __restrict__ A, unsigned short* __restrict__ S) {
    __shared__ float w1s[12][128];
    __shared__ float mus[128], rss[128];
    int t = threadIdx.x, wave = t >> 6, lane = t & 63, lr = lane & 15, lg = lane >> 4;
    int rt = blockIdx.x * 16;
    int b = blockIdx.x / (NB / 16);
    int fb = wave * 32;
    for (int i = t; i < 12 * 128; i += 256) w1s[i >> 7][i & 127] = w1u[i];
    if (t < 128) { mus[t] = musig[b * 128 + t]; rss[t] = musig[256 + b * 128 + t]; }
    __syncthreads();
    f32x4 accA[2], accS[2];
    accA[0] = (f32x4)0.0f; accA[1] = (f32x4)0.0f;
    accS[0] = (f32x4)0.0f; accS[1] = (f32x4)0.0f;
#pragma unroll
    for (int kc = 0; kc < 4; ++kc) {
        int k0 = kc * 32 + lg * 8;
        bf16x8 a = norm_frag(hf + (size_t)(rt + lr) * HF + k0, mus, rss, k0);
#pragma unroll
        for (int j = 0; j < 2; ++j) {
            bf16x8 bA = *(const bf16x8*)(wA + (size_t)(fb + j * 16 + lr) * HF + k0);
            accA[j] = MFMA16(a, bA, accA[j]);
            bf16x8 bS = *(const bf16x8*)(wB + (size_t)(fb + j * 16 + lr) * HF + k0);
            accS[j] = MFMA16(a, bS, accS[j]);
        }
    }
    float ni[4][12];
#pragma unroll
    for (int r = 0; r < 4; ++r) {
        const float4* np = (const float4*)(nodein + (size_t)(rt + lg * 4 + r) * 16);
        float4 v0 = np[0], v1 = np[1], v2 = np[2];
        ni[r][0] = v0.x; ni[r][1] = v0.y; ni[r][2] = v0.z; ni[r][3] = v0.w;
        ni[r][4] = v1.x; ni[r][5] = v1.y; ni[r][6] = v1.z; ni[r][7] = v1.w;
        ni[r][8] = v2.x; ni[r][9] = v2.y; ni[r][10] = v2.z; ni[r][11] = v2.w;
    }
#pragma unroll
    for (int j = 0; j < 2; ++j) {
        int f = fb + j * 16 + lr;
        float au[4] = {0.f, 0.f, 0.f, 0.f};
#pragma unroll
        for (int k = 0; k < 12; ++k) {
            float wv = w1s[k][f];
#pragma unroll
            for (int r = 0; r < 4; ++r) au[r] = fmaf(ni[r][k], wv, au[r]);
        }
#pragma unroll
        for (int r = 0; r < 4; ++r) {
            size_t o = (size_t)(rt + lg * 4 + r) * HF + f;
            A[o] = f2b(accA[j][r] + au[r]);
            S[o] = f2b(accS[j][r] - au[r]);
        }
    }
}

// ---------------- message + aggregate: phase1 all-z -> 1 barrier -> phase2 all-MFMA ----------------
__global__ __launch_bounds__(256, 4)
void k_agg(const unsigned short* __restrict__ Ab, const unsigned short* __restrict__ Sb,
           const unsigned short* __restrict__ wT2, const float* __restrict__ b2,
           const float* __restrict__ b1, const float* __restrict__ w1d,
           unsigned short* __restrict__ aggb) {
    __shared__ float dsb[3][128];
    __shared__ char exb[9 * 4096];       // z frags for all 9 offsets
    int t = threadIdx.x, kq = t >> 6, lane = t & 63, lr = lane & 15, lg = lane >> 4;
    int bx = blockIdx.x;
    int b = bx / (NB / 16), tile = bx % (NB / 16);
    int rt = tile * 16;                  // 16 | 96 -> single grid row R
    int fb = kq * 32;
    size_t bN = (size_t)b * NB;
    int R = rt / GW, C0 = rt % GW;

    if (t < 128) {
        float bb = b1[t], wd = w1d[t];
        dsb[0][t] = bb;
        dsb[1][t] = fmaf(1.0f / 95.0f, wd, bb);
        dsb[2][t] = fmaf(1.4142135623730951f / 95.0f, wd, bb);
    }
    bf16x8 w2f[2][4];
#pragma unroll
    for (int j = 0; j < 2; ++j)
#pragma unroll
        for (int kc = 0; kc < 4; ++kc)
            w2f[j][kc] = *(const bf16x8*)(wT2 + (size_t)(fb + j * 16 + lr) * HF
                                          + kc * 32 + lg * 8);
    int rowA = rt + lr;
    float Af[8];
    {
        bf16x8 av = *(const bf16x8*)(Ab + (bN + rowA) * HF + kq * 32 + lg * 8);
#pragma unroll
        for (int e = 0; e < 8; ++e) Af[e] = b2f((unsigned short)av[e]);
    }
    float b2r[2] = { b2[fb + lr], b2[fb + 16 + lr] };
    int lofs = lane * 16;
    __syncthreads();   // dsb ready

    // ---- phase 1: z for all 9 offsets (own k-quarter), prefetch depth 1 ----
    bf16x8 sv;
    {
        int src = min(max(rowA - 97, 0), NB - 1);
        sv = *(const bf16x8*)(Sb + (bN + src) * HF + kq * 32 + lg * 8);
    }
#pragma unroll
    for (int off = 0; off < 9; ++off) {
        int dr = off / 3 - 1, dc = off % 3 - 1;
        int dd = dr * dr + dc * dc;
        bf16x8 cur = sv;
        if (off < 8) {
            int no = off + 1;
            int dnn = (no / 3 - 1) * GW + (no % 3 - 1);
            int src = min(max(rowA + dnn, 0), NB - 1);
            sv = *(const bf16x8*)(Sb + (bN + src) * HF + kq * 32 + lg * 8);
        }
        const float* dp = &dsb[dd][kq * 32 + lg * 8];
        union { bf16x8 v; unsigned u[4]; } az;
#pragma unroll
        for (int q = 0; q < 4; ++q) {
            float zl = swishf(Af[2 * q]     + b2f((unsigned short)cur[2 * q])     + dp[2 * q]);
            float zh = swishf(Af[2 * q + 1] + b2f((unsigned short)cur[2 * q + 1]) + dp[2 * q + 1]);
            az.u[q] = (unsigned)f2b(zl) | ((unsigned)f2b(zh) << 16);
        }
        *(bf16x8*)(exb + off * 4096 + kq * 1024 + lofs) = az.v;
    }
    __syncthreads();

    // ---- phase 2: barrier-free MFMA + epilogue over all 9 offsets ----
    f32x4 agg2[2];
    agg2[0] = (f32x4)0.0f; agg2[1] = (f32x4)0.0f;
#pragma unroll
    for (int off = 0; off < 9; ++off) {
        int dr = off / 3 - 1, dc = off % 3 - 1;
        f32x4 acc[2];
        acc[0] = (f32x4)0.0f; acc[1] = (f32x4)0.0f;
#pragma unroll
        for (int kc = 0; kc < 4; ++kc) {
            bf16x8 a = *(const bf16x8*)(exb + off * 4096 + kc * 1024 + lofs);
            acc[0] = MFMA16(a, w2f[0][kc], acc[0]);
            acc[1] = MFMA16(a, w2f[1][kc], acc[1]);
        }
        bool rOK = (unsigned)(R + dr) < (unsigned)GH;
#pragma unroll
        for (int j = 0; j < 2; ++j)
#pragma unroll
            for (int r = 0; r < 4; ++r) {
                int C = C0 + lg * 4 + r;
                if (rOK && (unsigned)(C + dc) < (unsigned)GW)
                    agg2[j][r] += swishf(acc[j][r] + b2r[j]);
            }
    }
    float nr = 1.0f + (R > 0) + (R < GH - 1);
#pragma unroll
    for (int j = 0; j < 2; ++j)
#pragma unroll
        for (int r = 0; r < 4; ++r) {
            int n = rt + lg * 4 + r;
            int C = C0 + lg * 4 + r;
            float nc = 1.0f + (C > 0) + (C < GW - 1);
            aggb[(bN + n) * HF + fb + j * 16 + lr] =
                f2b(__fdividef(agg2[j][r], nr * nc));
        }
}

// ---------------- fused update MLP (norm-on-read):
// t1 = swish(norm(hf)@W1a + aggb@W1b + b1); v = swish(t1@W2 + b2) + norm(hf);
// hf <- v (raw); partial stats on v ----------------
__global__ __launch_bounds__(256, 4)
void k_upd(float* __restrict__ hf, const float* __restrict__ musig,
           const unsigned short* __restrict__ aggb,
           const unsigned short* __restrict__ w1a, const unsigned short* __restrict__ w1b,
           const unsigned short* __restrict__ w2, const float* __restrict__ b1v,
           const float* __restrict__ b2v, float* __restrict__ partial) {
    __shared__ char t1s[4096];
    __shared__ float mus[128], rss[128];
    int t = threadIdx.x, wave = t >> 6, lane = t & 63, lr = lane & 15, lg = lane >> 4;
    int rt = blockIdx.x * 16;
    int b = blockIdx.x / (NB / 16);
    int fb = wave * 32;
    if (t < 128) { mus[t] = musig[b * 128 + t]; rss[t] = musig[256 + b * 128 + t]; }
    __syncthreads();
    // GEMM1 (dual input)
    f32x4 acc[2];
    acc[0] = (f32x4)0.0f; acc[1] = (f32x4)0.0f;
#pragma unroll
    for (int kc = 0; kc < 4; ++kc) {
        int k0 = kc * 32 + lg * 8;
        bf16x8 a1 = norm_frag(hf + (size_t)(rt + lr) * HF + k0, mus, rss, k0);
        bf16x8 a2 = *(const bf16x8*)(aggb + (size_t)(rt + lr) * HF + k0);
#pragma unroll
        for (int j = 0; j < 2; ++j) {
            bf16x8 bA = *(const bf16x8*)(w1a + (size_t)(fb + j * 16 + lr) * HF + k0);
            acc[j] = MFMA16(a1, bA, acc[j]);
            bf16x8 bB = *(const bf16x8*)(w1b + (size_t)(fb + j * 16 + lr) * HF + k0);
            acc[j] = MFMA16(a2, bB, acc[j]);
        }
    }
    // t1 = swish(acc + b1) -> swizzled LDS
#pragma unroll
    for (int j = 0; j < 2; ++j) {
        int col = fb + j * 16 + lr;
        float bv = b1v[col];
#pragma unroll
        for (int r = 0; r < 4; ++r) {
            int row = lg * 4 + r;
            int addr = (row * 256 + col * 2) ^ ((row & 7) << 4);
            *(unsigned short*)(t1s + addr) = f2b(swishf(acc[j][r] + bv));
        }
    }
    __syncthreads();
    // GEMM2
    f32x4 acc2[2];
    acc2[0] = (f32x4)0.0f; acc2[1] = (f32x4)0.0f;
#pragma unroll
    for (int kc = 0; kc < 4; ++kc) {
        int k0 = kc * 32 + lg * 8;
        bf16x8 a = *(const bf16x8*)(t1s + ((lr * 256 + k0 * 2) ^ ((lr & 7) << 4)));
#pragma unroll
        for (int j = 0; j < 2; ++j) {
            bf16x8 b = *(const bf16x8*)(w2 + (size_t)(fb + j * 16 + lr) * HF + k0);
            acc2[j] = MFMA16(a, b, acc2[j]);
        }
    }
#pragma unroll
    for (int j = 0; j < 2; ++j) {
        int f = fb + j * 16 + lr;
        float bv = b2v[f];
        float mu = mus[f], rs = rss[f];
        float s1 = 0.f, s2 = 0.f;
#pragma unroll
        for (int r = 0; r < 4; ++r) {
            size_t o = (size_t)(rt + lg * 4 + r) * HF + f;
            float v = swishf(acc2[j][r] + bv) + (hf[o] - mu) * rs;
            hf[o] = v;
            s1 += v; s2 += v * v;
        }
        s1 += __shfl_xor(s1, 16); s1 += __shfl_xor(s1, 32);
        s2 += __shfl_xor(s2, 16); s2 += __shfl_xor(s2, 32);
        if (lg == 0) {
            float* p = partial + ((size_t)blockIdx.x * HF + f) * 2;
            p[0] = s1; p[1] = s2;
        }
    }
}

// ---------------- instance-norm stats reduce: 256 blocks, one (b,f) each ----------------
__global__ void k_stats(const float* __restrict__ partial, float* __restrict__ musig) {
    __shared__ float ss[256], qq[256];
    int bx = blockIdx.x;
    int b = bx >> 7, f = bx & 127;
    int t = threadIdx.x;
    float s = 0.f, q = 0.f;
    for (int i = t; i < 576; i += 256) {
        const float* p = partial + (((size_t)(b * 576 + i)) * HF + f) * 2;
        s += p[0]; q += p[1];
    }
    ss[t] = s; qq[t] = q;
    __syncthreads();
    for (int st = 128; st > 0; st >>= 1) {
        if (t < st) { ss[t] += ss[t + st]; qq[t] += qq[t + st]; }
        __syncthreads();
    }
    if (t == 0) {
        float mu = ss[0] * (1.0f / NB);
        float var = qq[0] * (1.0f / NB) - mu * mu;
        musig[bx] = mu;
        musig[256 + bx] = rsqrtf(var + 1e-5f);
    }
}

// ---------------- fused output head (norm-on-read):
// g1 = swish(norm(hf)@W1+b1); out = x[:,-1] + g1@W2 + b2 ----------------
__global__ __launch_bounds__(256, 4)
void k_out(const float* __restrict__ hf, const float* __restrict__ musig,
           const unsigned short* __restrict__ wT1, const float* __restrict__ b1,
           const float* __restrict__ w2, const float* __restrict__ b2,
           const float* __restrict__ x, float* __restrict__ out) {
    __shared__ float g1s[16][132];
    __shared__ float w2s[384];
    __shared__ float mus[128], rss[128];
    int t = threadIdx.x, wave = t >> 6, lane = t & 63, lr = lane & 15, lg = lane >> 4;
    int rt = blockIdx.x * 16;
    int b = blockIdx.x / (NB / 16);
    int fb = wave * 32;
    for (int i = t; i < 384; i += 256) w2s[i] = w2[i];
    if (t < 128) { mus[t] = musig[b * 128 + t]; rss[t] = musig[256 + b * 128 + t]; }
    __syncthreads();
    f32x4 acc[2];
    acc[0] = (f32x4)0.0f; acc[1] = (f32x4)0.0f;
#pragma unroll
    for (int kc = 0; kc < 4; ++kc) {
        int k0 = kc * 32 + lg * 8;
        bf16x8 a = norm_frag(hf + (size_t)(rt + lr) * HF + k0, mus, rss, k0);
#pragma unroll
        for (int j = 0; j < 2; ++j) {
            bf16x8 bfr = *(const bf16x8*)(wT1 + (size_t)(fb + j * 16 + lr) * HF + k0);
            acc[j] = MFMA16(a, bfr, acc[j]);
        }
    }
#pragma unroll
    for (int j = 0; j < 2; ++j) {
        int f = fb + j * 16 + lr;
        float bv = b1[f];
#pragma unroll
        for (int r = 0; r < 4; ++r)
            g1s[lg * 4 + r][f] = swishf(acc[j][r] + bv);
    }
    __syncthreads();
    if (t < 48) {
        int r = t / 3, c = t - (t / 3) * 3;
        int row = rt + r;
        int bb = row / NB, n = row - bb * NB;
        float a = b2[c];
#pragma unroll 8
        for (int k = 0; k < HF; ++k) a = fmaf(g1s[r][k], w2s[k * 3 + c], a);
        float xv = x[(((size_t)bb * 4 + 3) * 3 + c) * NB + n];
        out[((size_t)bb * 3 + c) * NB + n] = a + xv;
    }
}

extern "C" void kernel_launch(void* const* d_in, const int* in_sizes, int n_in,
                              void* d_out, int out_size, void* d_ws, size_t ws_size,
                              hipStream_t stream) {
    const float* x      = (const float*)d_in[0];
    const float* pos    = (const float*)d_in[3];
    const float* emb_w1 = (const float*)d_in[4];
    const float* emb_b1 = (const float*)d_in[5];
    const float* emb_b2 = (const float*)d_in[7];
    const float* msg_w1 = (const float*)d_in[8];
    const float* msg_b1 = (const float*)d_in[9];
    const float* msg_b2 = (const float*)d_in[11];
    const float* upd_b1 = (const float*)d_in[13];
    const float* upd_b2 = (const float*)d_in[15];
    const float* out_b1 = (const float*)d_in[17];
    const float* out_w2 = (const float*)d_in[18];
    const float* out_b2 = (const float*)d_in[19];

    float* w = (float*)d_ws;
    size_t off = 0;
    auto alloc = [&](size_t n) { float* p = w + off; off += n; return p; };
    float* nodein  = alloc((size_t)MROWS * 16);
    float* hf      = alloc((size_t)MROWS * HF);
    float* partial = alloc((size_t)1152 * HF * 2);
    float* musig   = alloc(512);
    unsigned short* aggb = (unsigned short*)alloc((size_t)MROWS * 64);
    unsigned short* Abf  = (unsigned short*)alloc((size_t)MROWS * 64);
    unsigned short* Sbf  = (unsigned short*)alloc((size_t)MROWS * 64);
    unsigned short* wT   = (unsigned short*)alloc((size_t)38 * 16384 / 2);
    (void)ws_size; (void)in_sizes; (void)n_in; (void)out_size;

    k_prep<<<38, 256, 0, stream>>>((const float*)d_in[6], (const float*)d_in[16],
                                   msg_w1, (const float*)d_in[10],
                                   (const float*)d_in[12], (const float*)d_in[14], wT);
    k_build<<<(MROWS + 255) / 256, 256, 0, stream>>>(x, pos, nodein, musig);
    k_emb<<<1152, 256, 0, stream>>>(nodein, emb_w1, emb_b1, wT + 0 * 16384, emb_b2, hf);
    for (int l = 0; l < LAYERS; ++l) {
        const unsigned short* wL = wT + (size_t)(2 + 6 * l) * 16384;
        const float* W1 = msg_w1 + (size_t)l * 269 * HF;
        k_as<<<1152, 256, 0, stream>>>(hf, musig, wL + 0 * 16384, wL + 1 * 16384,
                                       nodein, W1 + 256 * HF, Abf, Sbf);
        k_agg<<<1152, 256, 0, stream>>>(Abf, Sbf, wL + 2 * 16384, msg_b2 + l * HF,
                                        msg_b1 + l * HF, W1 + 268 * HF, aggb);
        k_upd<<<1152, 256, 0, stream>>>(hf, musig, aggb, wL + 3 * 16384, wL + 4 * 16384,
                                        wL + 5 * 16384, upd_b1 + l * HF,
                                        upd_b2 + l * HF, partial);
        k_stats<<<256, 256, 0, stream>>>(partial, musig);
    }
    k_out<<<1152, 256, 0, stream>>>(hf, musig, wT + 1 * 16384, out_b1, out_w2, out_b2,
                                    x, (float*)d_out);
}

// Round 11
// 459.573 us; speedup vs baseline: 4.3729x; 1.1375x over previous
//
#include <hip/hip_runtime.h>
#include <math.h>

#define HF 128
#define NB 9216          // nodes per batch (96*96)
#define BB 2
#define MROWS (BB*NB)    // 18432
#define GH 96
#define GW 96
#define LAYERS 6

typedef __attribute__((ext_vector_type(8))) short bf16x8;
typedef __attribute__((ext_vector_type(4))) float f32x4;

#define MFMA16(a, b, c) __builtin_amdgcn_mfma_f32_16x16x32_bf16(a, b, c, 0, 0, 0)

__device__ __forceinline__ float swishf(float x) {
    return __fdividef(x, 1.0f + __expf(-x));
}

// fp32 -> bf16 bits, round-to-nearest-even
__device__ __forceinline__ unsigned short f2b(float f) {
    unsigned u = __float_as_uint(f);
    unsigned r = (u + 0x7fffu + ((u >> 16) & 1u)) >> 16;
    return (unsigned short)r;
}
__device__ __forceinline__ float b2f(unsigned short u) {
    return __uint_as_float((unsigned)u << 16);
}

// normalize 8 hf values -> bf16x8 fragment
__device__ __forceinline__ bf16x8 norm_frag(const float* __restrict__ hp,
                                            const float* __restrict__ mus,
                                            const float* __restrict__ rss, int k0) {
    float4 h0 = *(const float4*)hp;
    float4 h1 = *(const float4*)(hp + 4);
    float4 m0 = *(const float4*)&mus[k0];
    float4 m1 = *(const float4*)&mus[k0 + 4];
    float4 r0 = *(const float4*)&rss[k0];
    float4 r1 = *(const float4*)&rss[k0 + 4];
    union { bf16x8 v; unsigned u[4]; } az;
    float a0 = (h0.x - m0.x) * r0.x, a1 = (h0.y - m0.y) * r0.y;
    az.u[0] = (unsigned)f2b(a0) | ((unsigned)f2b(a1) << 16);
    float a2 = (h0.z - m0.z) * r0.z, a3 = (h0.w - m0.w) * r0.w;
    az.u[1] = (unsigned)f2b(a2) | ((unsigned)f2b(a3) << 16);
    float a4 = (h1.x - m1.x) * r1.x, a5 = (h1.y - m1.y) * r1.y;
    az.u[2] = (unsigned)f2b(a4) | ((unsigned)f2b(a5) << 16);
    float a6 = (h1.z - m1.z) * r1.z, a7 = (h1.w - m1.w) * r1.w;
    az.u[3] = (unsigned)f2b(a6) | ((unsigned)f2b(a7) << 16);
    return az.v;
}

// finalize instance-norm stats in LDS (mraw=nullptr -> identity)
__device__ __forceinline__ void load_musig(const float* __restrict__ mraw, int b, int t,
                                           float* __restrict__ mus, float* __restrict__ rss) {
    if (t < 128) {
        float mu = 0.f, rs = 1.f;
        if (mraw) {
            float s = mraw[b * 128 + t], q = mraw[256 + b * 128 + t];
            mu = s * (1.0f / NB);
            float var = q * (1.0f / NB) - mu * mu;
            rs = rsqrtf(var + 1e-5f);
        }
        mus[t] = mu; rss[t] = rs;
    }
}

// ---------------- weight prep: wT[slot][col][k] = bf16(W[k][col]) ----------------
// slots: 0=emb_w2, 1=out_w1, 2+6l+{0..5} = msgW1a, msgW1b, msgW2, updW1a, updW1b, updW2
__global__ void k_prep(const float* __restrict__ embw2, const float* __restrict__ outw1,
                       const float* __restrict__ msgw1, const float* __restrict__ msgw2,
                       const float* __restrict__ updw1, const float* __restrict__ updw2,
                       unsigned short* __restrict__ wT) {
    int s = blockIdx.x;
    const float* src;
    if (s == 0) src = embw2;
    else if (s == 1) src = outw1;
    else {
        int l = (s - 2) / 6, r = (s - 2) % 6;
        if (r == 0)      src = msgw1 + (size_t)l * 269 * HF;
        else if (r == 1) src = msgw1 + (size_t)l * 269 * HF + HF * HF;
        else if (r == 2) src = msgw2 + (size_t)l * HF * HF;
        else if (r == 3) src = updw1 + (size_t)l * 256 * HF;
        else if (r == 4) src = updw1 + (size_t)l * 256 * HF + HF * HF;
        else             src = updw2 + (size_t)l * HF * HF;
    }
    __shared__ float tile[128][133];
    int t = threadIdx.x;
#pragma unroll
    for (int i = 0; i < 64; ++i) {
        int id = i * 256 + t;
        tile[id >> 7][id & 127] = src[id];
    }
    __syncthreads();
    unsigned short* o = wT + (size_t)s * 16384;
#pragma unroll
    for (int i = 0; i < 64; ++i) {
        int id = i * 256 + t;
        int col = id >> 7, k = id & 127;
        o[id] = f2b(tile[k][col]);
    }
}

// ---------------- build nodein [B,N,16]; zero stat accumulators ----------------
__global__ void k_build(const float* __restrict__ x, const float* __restrict__ pos,
                        float* __restrict__ nodein, float* __restrict__ msr) {
    int idx = blockIdx.x * 256 + threadIdx.x;
    if (idx < LAYERS * 512) msr[idx] = 0.0f;
    if (idx >= MROWS) return;
    int b = idx / NB, n = idx - b * NB;
    float* o = nodein + (size_t)idx * 16;
    const float* xb = x + (size_t)b * 12 * NB + n;
#pragma unroll
    for (int k = 0; k < 12; ++k) o[k] = xb[(size_t)k * NB];
    o[12] = pos[2 * n];
    o[13] = pos[2 * n + 1];
    o[14] = 0.0f; o[15] = 0.0f;
}

// ---------------- fused embedding: t1 = swish(nodein@W1+b1); hf = swish(t1@W2+b2) ----------------
__global__ __launch_bounds__(256, 4)
void k_emb(const float* __restrict__ nodein, const float* __restrict__ w1,
           const float* __restrict__ b1, const unsigned short* __restrict__ wT2,
           const float* __restrict__ b2, float* __restrict__ hf) {
    __shared__ float xs[16][14];
    __shared__ char t1s[4096];
    int t = threadIdx.x;
    int rt = blockIdx.x * 16;
    if (t < 224) {
        int r = t / 14, k = t - r * 14;
        xs[r][k] = nodein[(size_t)(rt + r) * 16 + k];
    }
    __syncthreads();
    {
        int f = t & 127, rblk = t >> 7;
        float wreg[14];
#pragma unroll
        for (int k = 0; k < 14; ++k) wreg[k] = w1[k * HF + f];
        float bv = b1[f];
#pragma unroll
        for (int i = 0; i < 8; ++i) {
            int row = rblk * 8 + i;
            float acc = bv;
#pragma unroll
            for (int k = 0; k < 14; ++k) acc = fmaf(xs[row][k], wreg[k], acc);
            int addr = (row * 256 + f * 2) ^ ((row & 7) << 4);
            *(unsigned short*)(t1s + addr) = f2b(swishf(acc));
        }
    }
    __syncthreads();
    int wave = t >> 6, lane = t & 63, lr = lane & 15, lg = lane >> 4;
    int fb = wave * 32;
    f32x4 acc[2];
    acc[0] = (f32x4)0.0f; acc[1] = (f32x4)0.0f;
#pragma unroll
    for (int kc = 0; kc < 4; ++kc) {
        int k0 = kc * 32 + lg * 8;
        bf16x8 a = *(const bf16x8*)(t1s + ((lr * 256 + k0 * 2) ^ ((lr & 7) << 4)));
#pragma unroll
        for (int j = 0; j < 2; ++j) {
            bf16x8 b = *(const bf16x8*)(wT2 + (size_t)(fb + j * 16 + lr) * HF + k0);
            acc[j] = MFMA16(a, b, acc[j]);
        }
    }
#pragma unroll
    for (int j = 0; j < 2; ++j) {
        int f = fb + j * 16 + lr;
        float bv = b2[f];
#pragma unroll
        for (int r = 0; r < 4; ++r) {
            size_t o = (size_t)(rt + lg * 4 + r) * HF + f;
            hf[o] = swishf(acc[j][r] + bv);
        }
    }
}

// ---------------- A/S projection (norm-on-read) with fused Au ----------------
// A = bf16(norm(hf)@W1a + nodein@W1u) ; S = bf16(norm(hf)@W1b - nodein@W1u)
__global__ __launch_bounds__(256, 4)
void k_as(const float* __restrict__ hf, const float* __restrict__ mraw,
          const unsigned short* __restrict__ wA, const unsigned short* __restrict__ wB,
          const float* __restrict__ nodein, const float* __restrict__ w1u,
          unsigned short* __restrict__ A, unsigned short* __restrict__ S) {
    __shared__ float w1s[12][128];
    __shared__ float mus[128], rss[128];
    int t = threadIdx.x, wave = t >> 6, lane = t & 63, lr = lane & 15, lg = lane >> 4;
    int rt = blockIdx.x * 16;
    int b = blockIdx.x / (NB / 16);
    int fb = wave * 32;
    for (int i = t; i < 12 * 128; i += 256) w1s[i >> 7][i & 127] = w1u[i];
    load_musig(mraw, b, t, mus, rss);
    __syncthreads();
    f32x4 accA[2], accS[2];
    accA[0] = (f32x4)0.0f; accA[1] = (f32x4)0.0f;
    accS[0] = (f32x4)0.0f; accS[1] = (f32x4)0.0f;
#pragma unroll
    for (int kc = 0; kc < 4; ++kc) {
        int k0 = kc * 32 + lg * 8;
        bf16x8 a = norm_frag(hf + (size_t)(rt + lr) * HF + k0, mus, rss, k0);
#pragma unroll
        for (int j = 0; j < 2; ++j) {
            bf16x8 bA = *(const bf16x8*)(wA + (size_t)(fb + j * 16 + lr) * HF + k0);
            accA[j] = MFMA16(a, bA, accA[j]);
            bf16x8 bS = *(const bf16x8*)(wB + (size_t)(fb + j * 16 + lr) * HF + k0);
            accS[j] = MFMA16(a, bS, accS[j]);
        }
    }
    float ni[4][12];
#pragma unroll
    for (int r = 0; r < 4; ++r) {
        const float4* np = (const float4*)(nodein + (size_t)(rt + lg * 4 + r) * 16);
        float4 v0 = np[0], v1 = np[1], v2 = np[2];
        ni[r][0] = v0.x; ni[r][1] = v0.y; ni[r][2] = v0.z; ni[r][3] = v0.w;
        ni[r][4] = v1.x; ni[r][5] = v1.y; ni[r][6] = v1.z; ni[r][7] = v1.w;
        ni[r][8] = v2.x; ni[r][9] = v2.y; ni[r][10] = v2.z; ni[r][11] = v2.w;
    }
#pragma unroll
    for (int j = 0; j < 2; ++j) {
        int f = fb + j * 16 + lr;
        float au[4] = {0.f, 0.f, 0.f, 0.f};
#pragma unroll
        for (int k = 0; k < 12; ++k) {
            float wv = w1s[k][f];
#pragma unroll
            for (int r = 0; r < 4; ++r) au[r] = fmaf(ni[r][k], wv, au[r]);
        }
#pragma unroll
        for (int r = 0; r < 4; ++r) {
            size_t o = (size_t)(rt + lg * 4 + r) * HF + f;
            A[o] = f2b(accA[j][r] + au[r]);
            S[o] = f2b(accS[j][r] - au[r]);
        }
    }
}

// ---------------- fused message+aggregate+update:
// agg = (1/deg) sum_off swish(swish(A+S+D)@W2m + b2m)      [phases 1-2]
// t1  = swish(norm(hf)@W1a + agg@W1b + b1u)                [phase 3]
// v   = swish(t1@W2u + b2u) + norm(hf); hf <- v; stats -> atomicAdd msr ----------------
__global__ __launch_bounds__(256, 4)
void k_aggupd(const unsigned short* __restrict__ Ab, const unsigned short* __restrict__ Sb,
              const unsigned short* __restrict__ wT2, const float* __restrict__ b2m,
              const float* __restrict__ b1m, const float* __restrict__ w1d,
              float* __restrict__ hf, const float* __restrict__ mraw,
              const unsigned short* __restrict__ w1a, const unsigned short* __restrict__ w1b,
              const unsigned short* __restrict__ w2u, const float* __restrict__ b1u,
              const float* __restrict__ b2u, float* __restrict__ msr) {
    __shared__ float dsb[3][128];
    __shared__ float mus[128], rss[128];
    __shared__ char exb[9 * 4096];       // z frags; later reused: agg tile @0, t1 @4096
    int t = threadIdx.x, kq = t >> 6, lane = t & 63, lr = lane & 15, lg = lane >> 4;
    int bx = blockIdx.x;
    int b = bx / (NB / 16), tile = bx % (NB / 16);
    int rt = tile * 16;                  // LOCAL row within batch (16 | 96)
    int fb = kq * 32;
    size_t bN = (size_t)b * NB;
    int R = rt / GW, C0 = rt % GW;

    if (t < 128) {
        float bb = b1m[t], wd = w1d[t];
        dsb[0][t] = bb;
        dsb[1][t] = fmaf(1.0f / 95.0f, wd, bb);
        dsb[2][t] = fmaf(1.4142135623730951f / 95.0f, wd, bb);
    }
    load_musig(mraw, b, t, mus, rss);
    bf16x8 w2f[2][4];
#pragma unroll
    for (int j = 0; j < 2; ++j)
#pragma unroll
        for (int kc = 0; kc < 4; ++kc)
            w2f[j][kc] = *(const bf16x8*)(wT2 + (size_t)(fb + j * 16 + lr) * HF
                                          + kc * 32 + lg * 8);
    int rowA = rt + lr;
    float Af[8];
    {
        bf16x8 av = *(const bf16x8*)(Ab + (bN + rowA) * HF + kq * 32 + lg * 8);
#pragma unroll
        for (int e = 0; e < 8; ++e) Af[e] = b2f((unsigned short)av[e]);
    }
    float b2r[2] = { b2m[fb + lr], b2m[fb + 16 + lr] };
    int lofs = lane * 16;
    __syncthreads();   // dsb/mus ready

    // ---- phase 1: z for all 9 offsets (own k-quarter), prefetch depth 1 ----
    bf16x8 sv;
    {
        int src = min(max(rowA - 97, 0), NB - 1);
        sv = *(const bf16x8*)(Sb + (bN + src) * HF + kq * 32 + lg * 8);
    }
#pragma unroll
    for (int off = 0; off < 9; ++off) {
        int dr = off / 3 - 1, dc = off % 3 - 1;
        int dd = dr * dr + dc * dc;
        bf16x8 cur = sv;
        if (off < 8) {
            int no = off + 1;
            int dnn = (no / 3 - 1) * GW + (no % 3 - 1);
            int src = min(max(rowA + dnn, 0), NB - 1);
            sv = *(const bf16x8*)(Sb + (bN + src) * HF + kq * 32 + lg * 8);
        }
        const float* dp = &dsb[dd][kq * 32 + lg * 8];
        union { bf16x8 v; unsigned u[4]; } az;
#pragma unroll
        for (int q = 0; q < 4; ++q) {
            float zl = swishf(Af[2 * q]     + b2f((unsigned short)cur[2 * q])     + dp[2 * q]);
            float zh = swishf(Af[2 * q + 1] + b2f((unsigned short)cur[2 * q + 1]) + dp[2 * q + 1]);
            az.u[q] = (unsigned)f2b(zl) | ((unsigned)f2b(zh) << 16);
        }
        *(bf16x8*)(exb + off * 4096 + kq * 1024 + lofs) = az.v;
    }
    __syncthreads();

    // ---- phase 2: MFMA + swish-accumulate over all 9 offsets ----
    f32x4 agg2[2];
    agg2[0] = (f32x4)0.0f; agg2[1] = (f32x4)0.0f;
#pragma unroll
    for (int off = 0; off < 9; ++off) {
        int dr = off / 3 - 1, dc = off % 3 - 1;
        f32x4 acc[2];
        acc[0] = (f32x4)0.0f; acc[1] = (f32x4)0.0f;
#pragma unroll
        for (int kc = 0; kc < 4; ++kc) {
            bf16x8 a = *(const bf16x8*)(exb + off * 4096 + kc * 1024 + lofs);
            acc[0] = MFMA16(a, w2f[0][kc], acc[0]);
            acc[1] = MFMA16(a, w2f[1][kc], acc[1]);
        }
        bool rOK = (unsigned)(R + dr) < (unsigned)GH;
#pragma unroll
        for (int j = 0; j < 2; ++j)
#pragma unroll
            for (int r = 0; r < 4; ++r) {
                int C = C0 + lg * 4 + r;
                if (rOK && (unsigned)(C + dc) < (unsigned)GW)
                    agg2[j][r] += swishf(acc[j][r] + b2r[j]);
            }
    }
    __syncthreads();   // z region dead; safe to reuse exb

    // ---- agg tile -> LDS (bf16, swizzled, rows local 0..15) ----
    float nr = 1.0f + (R > 0) + (R < GH - 1);
#pragma unroll
    for (int j = 0; j < 2; ++j)
#pragma unroll
        for (int r = 0; r < 4; ++r) {
            int row = lg * 4 + r;
            int C = C0 + row;
            float nc = 1.0f + (C > 0) + (C < GW - 1);
            int f = fb + j * 16 + lr;
            int addr = (row * 256 + f * 2) ^ ((row & 7) << 4);
            *(unsigned short*)(exb + addr) = f2b(__fdividef(agg2[j][r], nr * nc));
        }
    __syncthreads();

    // ---- phase 3: update GEMM1 (norm(hf), agg) — hf rows are GLOBAL (bN + rt) ----
    f32x4 acc[2];
    acc[0] = (f32x4)0.0f; acc[1] = (f32x4)0.0f;
#pragma unroll
    for (int kc = 0; kc < 4; ++kc) {
        int k0 = kc * 32 + lg * 8;
        bf16x8 a1 = norm_frag(hf + (bN + rt + lr) * HF + k0, mus, rss, k0);
        bf16x8 a2 = *(const bf16x8*)(exb + ((lr * 256 + k0 * 2) ^ ((lr & 7) << 4)));
#pragma unroll
        for (int j = 0; j < 2; ++j) {
            bf16x8 bA = *(const bf16x8*)(w1a + (size_t)(fb + j * 16 + lr) * HF + k0);
            acc[j] = MFMA16(a1, bA, acc[j]);
            bf16x8 bB = *(const bf16x8*)(w1b + (size_t)(fb + j * 16 + lr) * HF + k0);
            acc[j] = MFMA16(a2, bB, acc[j]);
        }
    }
    // t1 = swish(acc + b1u) -> swizzled LDS @4096
#pragma unroll
    for (int j = 0; j < 2; ++j) {
        int col = fb + j * 16 + lr;
        float bv = b1u[col];
#pragma unroll
        for (int r = 0; r < 4; ++r) {
            int row = lg * 4 + r;
            int addr = (row * 256 + col * 2) ^ ((row & 7) << 4);
            *(unsigned short*)(exb + 4096 + addr) = f2b(swishf(acc[j][r] + bv));
        }
    }
    __syncthreads();
    // GEMM2
    f32x4 acc2[2];
    acc2[0] = (f32x4)0.0f; acc2[1] = (f32x4)0.0f;
#pragma unroll
    for (int kc = 0; kc < 4; ++kc) {
        int k0 = kc * 32 + lg * 8;
        bf16x8 a = *(const bf16x8*)(exb + 4096 + ((lr * 256 + k0 * 2) ^ ((lr & 7) << 4)));
#pragma unroll
        for (int j = 0; j < 2; ++j) {
            bf16x8 bfr = *(const bf16x8*)(w2u + (size_t)(fb + j * 16 + lr) * HF + k0);
            acc2[j] = MFMA16(a, bfr, acc2[j]);
        }
    }
#pragma unroll
    for (int j = 0; j < 2; ++j) {
        int f = fb + j * 16 + lr;
        float bv = b2u[f];
        float mu = mus[f], rs = rss[f];
        float s1 = 0.f, s2 = 0.f;
#pragma unroll
        for (int r = 0; r < 4; ++r) {
            size_t o = (bN + rt + lg * 4 + r) * HF + f;
            float v = swishf(acc2[j][r] + bv) + (hf[o] - mu) * rs;
            hf[o] = v;
            s1 += v; s2 += v * v;
        }
        s1 += __shfl_xor(s1, 16); s1 += __shfl_xor(s1, 32);
        s2 += __shfl_xor(s2, 16); s2 += __shfl_xor(s2, 32);
        if (lg == 0) {
            atomicAdd(&msr[b * 128 + f], s1);
            atomicAdd(&msr[256 + b * 128 + f], s2);
        }
    }
}

// ---------------- fused output head (norm-on-read):
// g1 = swish(norm(hf)@W1+b1); out = x[:,-1] + g1@W2 + b2 ----------------
__global__ __launch_bounds__(256, 4)
void k_out(const float* __restrict__ hf, const float* __restrict__ mraw,
           const unsigned short* __restrict__ wT1, const float* __restrict__ b1,
           const float* __restrict__ w2, const float* __restrict__ b2,
           const float* __restrict__ x, float* __restrict__ out) {
    __shared__ float g1s[16][132];
    __shared__ float w2s[384];
    __shared__ float mus[128], rss[128];
    int t = threadIdx.x, wave = t >> 6, lane = t & 63, lr = lane & 15, lg = lane >> 4;
    int rt = blockIdx.x * 16;
    int b = blockIdx.x / (NB / 16);
    int fb = wave * 32;
    for (int i = t; i < 384; i += 256) w2s[i] = w2[i];
    load_musig(mraw, b, t, mus, rss);
    __syncthreads();
    f32x4 acc[2];
    acc[0] = (f32x4)0.0f; acc[1] = (f32x4)0.0f;
#pragma unroll
    for (int kc = 0; kc < 4; ++kc) {
        int k0 = kc * 32 + lg * 8;
        bf16x8 a = norm_frag(hf + (size_t)(rt + lr) * HF + k0, mus, rss, k0);
#pragma unroll
        for (int j = 0; j < 2; ++j) {
            bf16x8 bfr = *(const bf16x8*)(wT1 + (size_t)(fb + j * 16 + lr) * HF + k0);
            acc[j] = MFMA16(a, bfr, acc[j]);
        }
    }
#pragma unroll
    for (int j = 0; j < 2; ++j) {
        int f = fb + j * 16 + lr;
        float bv = b1[f];
#pragma unroll
        for (int r = 0; r < 4; ++r)
            g1s[lg * 4 + r][f] = swishf(acc[j][r] + bv);
    }
    __syncthreads();
    if (t < 48) {
        int r = t / 3, c = t - (t / 3) * 3;
        int row = rt + r;
        int bb = row / NB, n = row - bb * NB;
        float a = b2[c];
#pragma unroll 8
        for (int k = 0; k < HF; ++k) a = fmaf(g1s[r][k], w2s[k * 3 + c], a);
        float xv = x[(((size_t)bb * 4 + 3) * 3 + c) * NB + n];
        out[((size_t)bb * 3 + c) * NB + n] = a + xv;
    }
}

extern "C" void kernel_launch(void* const* d_in, const int* in_sizes, int n_in,
                              void* d_out, int out_size, void* d_ws, size_t ws_size,
                              hipStream_t stream) {
    const float* x      = (const float*)d_in[0];
    const float* pos    = (const float*)d_in[3];
    const float* emb_w1 = (const float*)d_in[4];
    const float* emb_b1 = (const float*)d_in[5];
    const float* emb_b2 = (const float*)d_in[7];
    const float* msg_w1 = (const float*)d_in[8];
    const float* msg_b1 = (const float*)d_in[9];
    const float* msg_b2 = (const float*)d_in[11];
    const float* upd_b1 = (const float*)d_in[13];
    const float* upd_b2 = (const float*)d_in[15];
    const float* out_b1 = (const float*)d_in[17];
    const float* out_w2 = (const float*)d_in[18];
    const float* out_b2 = (const float*)d_in[19];

    float* w = (float*)d_ws;
    size_t off = 0;
    auto alloc = [&](size_t n) { float* p = w + off; off += n; return p; };
    float* nodein  = alloc((size_t)MROWS * 16);
    float* hf      = alloc((size_t)MROWS * HF);
    float* msr     = alloc((size_t)LAYERS * 512);   // per-layer [sum|sumsq] accumulators
    unsigned short* Abf  = (unsigned short*)alloc((size_t)MROWS * 64);
    unsigned short* Sbf  = (unsigned short*)alloc((size_t)MROWS * 64);
    unsigned short* wT   = (unsigned short*)alloc((size_t)38 * 16384 / 2);
    (void)ws_size; (void)in_sizes; (void)n_in; (void)out_size;

    k_prep<<<38, 256, 0, stream>>>((const float*)d_in[6], (const float*)d_in[16],
                                   msg_w1, (const float*)d_in[10],
                                   (const float*)d_in[12], (const float*)d_in[14], wT);
    k_build<<<(MROWS + 255) / 256, 256, 0, stream>>>(x, pos, nodein, msr);
    k_emb<<<1152, 256, 0, stream>>>(nodein, emb_w1, emb_b1, wT + 0 * 16384, emb_b2, hf);
    for (int l = 0; l < LAYERS; ++l) {
        const unsigned short* wL = wT + (size_t)(2 + 6 * l) * 16384;
        const float* W1 = msg_w1 + (size_t)l * 269 * HF;
        const float* mprev = (l == 0) ? nullptr : msr + (size_t)(l - 1) * 512;
        k_as<<<1152, 256, 0, stream>>>(hf, mprev, wL + 0 * 16384, wL + 1 * 16384,
                                       nodein, W1 + 256 * HF, Abf, Sbf);
        k_aggupd<<<1152, 256, 0, stream>>>(Abf, Sbf, wL + 2 * 16384, msg_b2 + l * HF,
                                           msg_b1 + l * HF, W1 + 268 * HF,
                                           hf, mprev,
                                           wL + 3 * 16384, wL + 4 * 16384,
                                           wL + 5 * 16384, upd_b1 + l * HF,
                                           upd_b2 + l * HF, msr + (size_t)l * 512);
    }
    k_out<<<1152, 256, 0, stream>>>(hf, msr + (size_t)(LAYERS - 1) * 512,
                                    wT + 1 * 16384, out_b1, out_w2, out_b2,
                                    x, (float*)d_out);
}